// Round 1
// baseline (16815.509 us; speedup 1.0000x reference)
//
#include <hip/hip_runtime.h>

// ---- problem constants ----
#define DD 1024   // D
#define HH 2048   // H
#define TT 4096   // T
#define CC 512    // chunk
#define PPc 16    // persistent tokens
#define SSa 1040  // P + 2C
#define FFd 4096  // FFN
#define NCH 8     // T / C

typedef _Float16 f16x8 __attribute__((ext_vector_type(8)));
typedef float f32x4 __attribute__((ext_vector_type(4)));

#define BM 64
#define BN 64
#define BK 32
#define LDK 40   // padded LDS K-stride (80 B, 16B-aligned rows)

// Generic strided GEMM: C[M,N] = act(A@B + bias)*s1 + resid*s2
// A[m,k] = A[m*asM + k*asK], B[k,n] = B[k*bsK + n*bsN], C row stride csM.
// act: 0 none, 1 silu. Transposed operands assumed to have unit stride on the
// other axis (asK!=1 => asM==1; bsN!=1 => bsK==1) for vectorized staging.
__global__ __launch_bounds__(256) void gemm_k(
    const float* __restrict__ A, long asM, long asK,
    const float* __restrict__ B, long bsK, long bsN,
    float* __restrict__ Co, long csM,
    const float* __restrict__ bias,
    const float* __restrict__ resid, long rsM,
    float s1, float s2, int M, int N, int K, int act)
{
    __shared__ _Float16 As[BM][LDK] __attribute__((aligned(16)));
    __shared__ _Float16 Bs[BN][LDK] __attribute__((aligned(16)));
    const int tid = threadIdx.x;
    const int m0 = blockIdx.y * BM, n0 = blockIdx.x * BN;
    const int lane = tid & 63;
    const int wave = tid >> 6;
    const int wm = (wave & 1) * 32, wn = (wave >> 1) * 32;
    const int fr = lane & 15, kq = lane >> 4;
    f32x4 acc[2][2] = {};
    const bool a_kfast = (asK == 1);
    const bool b_nfast = (bsN == 1);

    for (int k0 = 0; k0 < K; k0 += BK) {
        // ---- stage A (BM x BK) into As[m][k] ----
        if (a_kfast) {
            const int kq4 = (tid & 7) * 4;
            const int rr = tid >> 3;
#pragma unroll
            for (int i = 0; i < 2; ++i) {
                const int r = rr + i * 32;
                const int gm = m0 + r, gk = k0 + kq4;
                float4 v = {0.f, 0.f, 0.f, 0.f};
                if (gm < M && gk < K) v = *(const float4*)(A + (long)gm * asM + gk);
                As[r][kq4 + 0] = (_Float16)v.x;
                As[r][kq4 + 1] = (_Float16)v.y;
                As[r][kq4 + 2] = (_Float16)v.z;
                As[r][kq4 + 3] = (_Float16)v.w;
            }
        } else {  // asM == 1: vectorize along m
            const int m4 = (tid & 15) * 4;
            const int kk0 = tid >> 4;
#pragma unroll
            for (int i = 0; i < 2; ++i) {
                const int kk = kk0 + i * 16;
                const int gm = m0 + m4, gk = k0 + kk;
                float4 v = {0.f, 0.f, 0.f, 0.f};
                if (gm < M && gk < K) v = *(const float4*)(A + gm + (long)gk * asK);
                As[m4 + 0][kk] = (_Float16)v.x;
                As[m4 + 1][kk] = (_Float16)v.y;
                As[m4 + 2][kk] = (_Float16)v.z;
                As[m4 + 3][kk] = (_Float16)v.w;
            }
        }
        // ---- stage B (BN x BK) into Bs[n][k] ----
        if (b_nfast) {
            const int n4 = (tid & 15) * 4;
            const int kk0 = tid >> 4;
#pragma unroll
            for (int i = 0; i < 2; ++i) {
                const int kk = kk0 + i * 16;
                const int gn = n0 + n4, gk = k0 + kk;
                float4 v = {0.f, 0.f, 0.f, 0.f};
                if (gn < N && gk < K) v = *(const float4*)(B + (long)gk * bsK + gn);
                Bs[n4 + 0][kk] = (_Float16)v.x;
                Bs[n4 + 1][kk] = (_Float16)v.y;
                Bs[n4 + 2][kk] = (_Float16)v.z;
                Bs[n4 + 3][kk] = (_Float16)v.w;
            }
        } else {  // bsK == 1: vectorize along k
            const int kq4 = (tid & 7) * 4;
            const int nn0 = tid >> 3;
#pragma unroll
            for (int i = 0; i < 2; ++i) {
                const int nn = nn0 + i * 32;
                const int gn = n0 + nn, gk = k0 + kq4;
                float4 v = {0.f, 0.f, 0.f, 0.f};
                if (gn < N && gk < K) v = *(const float4*)(B + (long)gn * bsN + gk);
                Bs[nn][kq4 + 0] = (_Float16)v.x;
                Bs[nn][kq4 + 1] = (_Float16)v.y;
                Bs[nn][kq4 + 2] = (_Float16)v.z;
                Bs[nn][kq4 + 3] = (_Float16)v.w;
            }
        }
        __syncthreads();
        f16x8 af0 = *(const f16x8*)&As[wm + fr][kq * 8];
        f16x8 af1 = *(const f16x8*)&As[wm + 16 + fr][kq * 8];
        f16x8 bg0 = *(const f16x8*)&Bs[wn + fr][kq * 8];
        f16x8 bg1 = *(const f16x8*)&Bs[wn + 16 + fr][kq * 8];
        acc[0][0] = __builtin_amdgcn_mfma_f32_16x16x32_f16(af0, bg0, acc[0][0], 0, 0, 0);
        acc[0][1] = __builtin_amdgcn_mfma_f32_16x16x32_f16(af0, bg1, acc[0][1], 0, 0, 0);
        acc[1][0] = __builtin_amdgcn_mfma_f32_16x16x32_f16(af1, bg0, acc[1][0], 0, 0, 0);
        acc[1][1] = __builtin_amdgcn_mfma_f32_16x16x32_f16(af1, bg1, acc[1][1], 0, 0, 0);
        __syncthreads();
    }
#pragma unroll
    for (int mt = 0; mt < 2; ++mt)
#pragma unroll
        for (int nt = 0; nt < 2; ++nt) {
            const int gn = n0 + wn + nt * 16 + fr;
            if (gn >= N) continue;
            const float bv = bias ? bias[gn] : 0.f;
#pragma unroll
            for (int r = 0; r < 4; ++r) {
                const int gm = m0 + wm + mt * 16 + kq * 4 + r;
                if (gm >= M) continue;
                float v = acc[mt][nt][r] + bv;
                if (act == 1) v = v / (1.f + __expf(-v));
                v *= s1;
                if (resid) v += s2 * resid[(long)gm * rsM + gn];
                Co[(long)gm * csM + gn] = v;
            }
        }
}

// ---- rowwise ops over D=1024, block=256, 4 elems/thread ----
__global__ void l2n_k(float* __restrict__ x, float scale)
{
    const long row = blockIdx.x;
    float* p = x + row * DD;
    const int t = threadIdx.x;
    float e0 = p[t], e1 = p[t + 256], e2 = p[t + 512], e3 = p[t + 768];
    __shared__ float rq[256];
    rq[t] = e0 * e0 + e1 * e1 + e2 * e2 + e3 * e3;
    __syncthreads();
    for (int k = 128; k; k >>= 1) {
        if (t < k) rq[t] += rq[t + k];
        __syncthreads();
    }
    const float n = sqrtf(rq[0]);
    const float f = scale / fmaxf(n, 1e-12f);
    p[t] = e0 * f; p[t + 256] = e1 * f; p[t + 512] = e2 * f; p[t + 768] = e3 * f;
}

__global__ void ln_k(const float* __restrict__ x, const float* __restrict__ g,
                     const float* __restrict__ b, float* __restrict__ o)
{
    const long row = blockIdx.x;
    const float* p = x + row * DD;
    float* q = o + row * DD;
    const int t = threadIdx.x;
    float e0 = p[t], e1 = p[t + 256], e2 = p[t + 512], e3 = p[t + 768];
    __shared__ float rs[256], rq[256];
    rs[t] = e0 + e1 + e2 + e3;
    rq[t] = e0 * e0 + e1 * e1 + e2 * e2 + e3 * e3;
    __syncthreads();
    for (int k = 128; k; k >>= 1) {
        if (t < k) { rs[t] += rs[t + k]; rq[t] += rq[t + k]; }
        __syncthreads();
    }
    const float mean = rs[0] * (1.f / DD);
    const float var = rq[0] * (1.f / DD) - mean * mean;
    const float inv = rsqrtf(var + 1e-5f);
    q[t]       = (e0 - mean) * inv * g[t]       + b[t];
    q[t + 256] = (e1 - mean) * inv * g[t + 256] + b[t + 256];
    q[t + 512] = (e2 - mean) * inv * g[t + 512] + b[t + 512];
    q[t + 768] = (e3 - mean) * inv * g[t + 768] + b[t + 768];
}

// masked softmax over scores [2*S][S]; row i (within batch): allow j<P or j<=i
__global__ void softmax_k(float* __restrict__ sc)
{
    const int row = blockIdx.x;      // 0..2079
    const int i = row % SSa;
    float* p = sc + (long)row * SSa;
    const int t = threadIdx.x;
    __shared__ float red[256];
    float mx = -3.0e38f;
    for (int j = t; j < SSa; j += 256)
        if (j < PPc || j <= i) mx = fmaxf(mx, p[j]);
    red[t] = mx; __syncthreads();
    for (int k = 128; k; k >>= 1) {
        if (t < k) red[t] = fmaxf(red[t], red[t + k]);
        __syncthreads();
    }
    mx = red[0];
    __syncthreads();
    float sum = 0.f;
    for (int j = t; j < SSa; j += 256) {
        float e = 0.f;
        if (j < PPc || j <= i) e = __expf(p[j] - mx);
        p[j] = e; sum += e;
    }
    red[t] = sum; __syncthreads();
    for (int k = 128; k; k >>= 1) {
        if (t < k) red[t] += red[t + k];
        __syncthreads();
    }
    const float inv = 1.f / red[0];
    for (int j = t; j < SSa; j += 256) p[j] *= inv;
}

// aug rows: [pers(16) | h(512) | seg(512)] per batch; 2080 blocks, 1 float4/thread
__global__ void build_aug_k(const float* __restrict__ x, const float* __restrict__ pers,
                            const float* __restrict__ h, float* __restrict__ aug, int c)
{
    const int row = blockIdx.x;
    const int b = row / SSa, s = row % SSa;
    const float* src;
    if (s < PPc) src = pers + (long)s * DD;
    else if (s < PPc + CC) src = h + ((long)(b * CC + s - PPc)) * DD;
    else src = x + ((long)(b * TT + c * CC + (s - PPc - CC))) * DD;
    ((float4*)(aug + (long)row * DD))[threadIdx.x] = ((const float4*)src)[threadIdx.x];
}

__global__ void copy_yt_k(const float* __restrict__ yaug, float* __restrict__ yt)
{
    const int row = blockIdx.x;  // 0..1023
    const int b = row >> 9, t = row & 511;
    const float4* src = (const float4*)(yaug + ((long)(b * SSa + PPc + CC + t)) * DD);
    ((float4*)(yt + (long)row * DD))[threadIdx.x] = src[threadIdx.x];
}

__global__ void silu_k(const float* __restrict__ a, float* __restrict__ o, long n)
{
    long i = (long)blockIdx.x * 256 + threadIdx.x;
    const long st = (long)gridDim.x * 256;
    for (; i < n; i += st) {
        const float x = a[i];
        o[i] = x / (1.f + __expf(-x));
    }
}

// da = dh * silu'(a0)
__global__ void silu_bwd_k(const float* __restrict__ dh, const float* __restrict__ a0,
                           float* __restrict__ da, long n)
{
    long i = (long)blockIdx.x * 256 + threadIdx.x;
    const long st = (long)gridDim.x * 256;
    for (; i < n; i += st) {
        const float a = a0[i];
        const float s = 1.f / (1.f + __expf(-a));
        da[i] = dh[i] * (s * (1.f + a * (1.f - s)));
    }
}

__global__ void colsum_k(const float* __restrict__ X, float* __restrict__ out, int M, int N)
{
    const int col = blockIdx.x * 256 + threadIdx.x;
    const int per = (M + gridDim.y - 1) / gridDim.y;
    const int r0 = blockIdx.y * per;
    int r1 = r0 + per; if (r1 > M) r1 = M;
    float s = 0.f;
    for (int r = r0; r < r1; ++r) s += X[(long)r * N + col];
    atomicAdd(&out[col], s);
}

__global__ void zero_k(float* __restrict__ p, long n)
{
    long i = (long)blockIdx.x * 256 + threadIdx.x;
    const long st = (long)gridDim.x * 256;
    for (; i < n; i += st) p[i] = 0.f;
}

__global__ void update_k(float* __restrict__ mem, float* __restrict__ mom,
                         const float* __restrict__ g, long n)
{
    long i = (long)blockIdx.x * 256 + threadIdx.x;
    const long st = (long)gridDim.x * 256;
    for (; i < n; i += st) {
        const float m = 0.9f * mom[i] + g[i];
        mom[i] = m;
        mem[i] = 0.99f * mem[i] - 0.01f * m;
    }
}

__global__ void gate_k(const float* __restrict__ yt, const float* __restrict__ gp,
                       const float* __restrict__ mo, float* __restrict__ o, long n)
{
    long i = (long)blockIdx.x * 256 + threadIdx.x;
    const long st = (long)gridDim.x * 256;
    for (; i < n; i += st) {
        const float s = 1.f / (1.f + __expf(-gp[i]));
        o[i] = yt[i] * s + mo[i] * (1.f - s);
    }
}

extern "C" void kernel_launch(void* const* d_in, const int* in_sizes, int n_in,
                              void* d_out, int out_size, void* d_ws, size_t ws_size,
                              hipStream_t stream)
{
    const float* x          = (const float*)d_in[0];
    const float* wq_ctx     = (const float*)d_in[1];
    const float* wq         = (const float*)d_in[2];
    const float* wk         = (const float*)d_in[3];
    const float* wv         = (const float*)d_in[4];
    const float* w_attn_out = (const float*)d_in[5];
    const float* w_gate     = (const float*)d_in[6];
    const float* gate_g     = (const float*)d_in[7];
    const float* gate_b     = (const float*)d_in[8];
    const float* n1_g       = (const float*)d_in[9];
    const float* n1_b       = (const float*)d_in[10];
    const float* n2_g       = (const float*)d_in[11];
    const float* n2_b       = (const float*)d_in[12];
    const float* ffn_w1     = (const float*)d_in[13];
    const float* ffn_b1     = (const float*)d_in[14];
    const float* ffn_w2     = (const float*)d_in[15];
    const float* ffn_b2     = (const float*)d_in[16];
    const float* pers       = (const float*)d_in[17];
    const float* mem_w0_in  = (const float*)d_in[18];
    const float* mem_b0_in  = (const float*)d_in[19];
    const float* mem_w1_in  = (const float*)d_in[20];
    const float* mem_b1_in  = (const float*)d_in[21];
    const float* mem_wk     = (const float*)d_in[22];
    const float* mem_wv     = (const float*)d_in[23];
    float* out = (float*)d_out;

    float* w = (float*)d_ws;
    size_t off = 0;
    auto alloc = [&](size_t n) { float* p = w + off; off += n; return p; };
    float* mem_w0 = alloc(DD * HH);
    float* mem_w1 = alloc(HH * DD);
    float* mem_b0 = alloc(HH);
    float* mem_b1 = alloc(DD);
    float* momblk = alloc((size_t)DD * HH * 2 + HH + DD);
    float* mom_w0 = momblk;
    float* mom_w1 = momblk + DD * HH;
    float* mom_b0 = mom_w1 + HH * DD;
    float* mom_b1 = mom_b0 + HH;
    float* S_xn  = alloc(1048576);           // xn / qn
    float* S_h   = alloc(1048576);           // h / y_t
    float* S_hsA = alloc(2097152);           // hsil / a0
    float* S_hs  = alloc(2097152);           // hs = silu(a0)
    float* S_dh  = alloc(2097152);           // dh / hs2
    float* S_dW0 = alloc(2097152);
    float* S_aug = alloc((size_t)2 * SSa * DD);   // aug / da0
    float* S_laug= alloc((size_t)2 * SSa * DD);   // ln(aug) / attn out
    float* S_qb  = alloc((size_t)2 * SSa * DD);   // q / y_aug
    float* S_kb  = alloc((size_t)2 * SSa * DD);   // k ; f1 overlays kb+vb
    float* S_vb  = alloc((size_t)2 * SSa * DD);   // v
    float* S_sc  = alloc((size_t)2 * SSa * SSa);  // scores / dW1
    float* S_kk  = alloc(1048576);
    float* S_vv  = alloc(1048576);
    float* S_r   = alloc(1048576);
    float* S_mo  = alloc(1048576);
    float* S_gl  = alloc(1048576);           // gate-ln / h2
    float* S_gp  = alloc(1048576);
    float* S_o   = alloc(1048576);
    float* S_db0 = alloc(HH);
    float* S_db1 = alloc(DD);
    (void)in_sizes; (void)n_in; (void)out_size; (void)ws_size;

    // init persistent state (ws is re-poisoned before every call)
    hipMemcpyAsync(mem_w0, mem_w0_in, sizeof(float) * DD * HH, hipMemcpyDeviceToDevice, stream);
    hipMemcpyAsync(mem_w1, mem_w1_in, sizeof(float) * HH * DD, hipMemcpyDeviceToDevice, stream);
    hipMemcpyAsync(mem_b0, mem_b0_in, sizeof(float) * HH, hipMemcpyDeviceToDevice, stream);
    hipMemcpyAsync(mem_b1, mem_b1_in, sizeof(float) * DD, hipMemcpyDeviceToDevice, stream);
    zero_k<<<4096, 256, 0, stream>>>(momblk, (long)DD * HH * 2 + HH + DD);

    auto gemm = [&](const float* A, long asM, long asK, const float* B, long bsK, long bsN,
                    float* C, long csM, const float* bias, const float* resid, long rsM,
                    float s1, float s2, int M, int N, int K, int act) {
        dim3 g((N + BN - 1) / BN, (M + BM - 1) / BM);
        gemm_k<<<g, 256, 0, stream>>>(A, asM, asK, B, bsK, bsN, C, csM, bias, resid, rsM,
                                      s1, s2, M, N, K, act);
    };

    for (int c = 0; c < NCH; ++c) {
        // xn = l2norm(seg @ wq_ctx)   (per-batch, seg rows live inside x)
        for (int b = 0; b < 2; ++b)
            gemm(x + ((long)b * TT + c * CC) * DD, DD, 1, wq_ctx, DD, 1,
                 S_xn + (long)b * CC * DD, DD, nullptr, nullptr, 0, 1.f, 0.f, CC, DD, DD, 0);
        l2n_k<<<1024, 256, 0, stream>>>(S_xn, 1.f);
        // h = mem_mlp(mem, xn)
        gemm(S_xn, DD, 1, mem_w0, HH, 1, S_hsA, HH, mem_b0, nullptr, 0, 1.f, 0.f, 1024, HH, DD, 1);
        gemm(S_hsA, HH, 1, mem_w1, DD, 1, S_h, DD, mem_b1, nullptr, 0, 1.f, 0.f, 1024, DD, HH, 0);
        // aug + LN
        build_aug_k<<<2 * SSa, 256, 0, stream>>>(x, pers, S_h, S_aug, c);
        ln_k<<<2 * SSa, 256, 0, stream>>>(S_aug, n1_g, n1_b, S_laug);
        // q,k,v
        gemm(S_laug, DD, 1, wq, DD, 1, S_qb, DD, nullptr, nullptr, 0, 1.f, 0.f, 2 * SSa, DD, DD, 0);
        l2n_k<<<2 * SSa, 256, 0, stream>>>(S_qb, 32.f);
        gemm(S_laug, DD, 1, wk, DD, 1, S_kb, DD, nullptr, nullptr, 0, 1.f, 0.f, 2 * SSa, DD, DD, 0);
        l2n_k<<<2 * SSa, 256, 0, stream>>>(S_kb, 1.f);
        gemm(S_laug, DD, 1, wv, DD, 1, S_vb, DD, nullptr, nullptr, 0, 1.f, 0.f, 2 * SSa, DD, DD, 0);
        // scores = q @ k^T per batch, masked softmax, attn = probs @ v
        for (int b = 0; b < 2; ++b)
            gemm(S_qb + (long)b * SSa * DD, DD, 1, S_kb + (long)b * SSa * DD, 1, DD,
                 S_sc + (long)b * SSa * SSa, SSa, nullptr, nullptr, 0, 1.f, 0.f, SSa, SSa, DD, 0);
        softmax_k<<<2 * SSa, 256, 0, stream>>>(S_sc);
        for (int b = 0; b < 2; ++b)
            gemm(S_sc + (long)b * SSa * SSa, SSa, 1, S_vb + (long)b * SSa * DD, DD, 1,
                 S_laug + (long)b * SSa * DD, DD, nullptr, nullptr, 0, 1.f, 0.f, SSa, DD, SSa, 0);
        // y_aug = aug + attn @ w_attn_out ; y_t = last C rows
        gemm(S_laug, DD, 1, w_attn_out, DD, 1, S_qb, DD, nullptr, S_aug, DD, 1.f, 1.f, 2 * SSa, DD, DD, 0);
        copy_yt_k<<<1024, 256, 0, stream>>>(S_qb, S_h);
        // kk, vv
        gemm(S_h, DD, 1, mem_wk, DD, 1, S_kk, DD, nullptr, nullptr, 0, 1.f, 0.f, 1024, DD, DD, 0);
        gemm(S_h, DD, 1, mem_wv, DD, 1, S_vv, DD, nullptr, nullptr, 0, 1.f, 0.f, 1024, DD, DD, 0);
        // forward mem MLP on kk (keep pre-act), r = (pred - vv)/1024
        gemm(S_kk, DD, 1, mem_w0, HH, 1, S_hsA, HH, mem_b0, nullptr, 0, 1.f, 0.f, 1024, HH, DD, 0);
        silu_k<<<2048, 256, 0, stream>>>(S_hsA, S_hs, (long)1024 * HH);
        gemm(S_hs, HH, 1, mem_w1, DD, 1, S_r, DD, mem_b1, S_vv, DD,
             1.f / 1024.f, -1.f / 1024.f, 1024, DD, HH, 0);
        // dW1 = hs^T @ r ; db1 = colsum(r)
        gemm(S_hs, 1, HH, S_r, DD, 1, S_sc, DD, nullptr, nullptr, 0, 1.f, 0.f, HH, DD, 1024, 0);
        zero_k<<<8, 256, 0, stream>>>(S_db1, DD);
        colsum_k<<<dim3(DD / 256, 16), 256, 0, stream>>>(S_r, S_db1, 1024, DD);
        // dh = r @ w1^T ; da0 = dh * silu'(a0)
        gemm(S_r, DD, 1, mem_w1, 1, DD, S_dh, HH, nullptr, nullptr, 0, 1.f, 0.f, 1024, HH, DD, 0);
        silu_bwd_k<<<2048, 256, 0, stream>>>(S_dh, S_hsA, S_aug, (long)1024 * HH);
        // dW0 = kk^T @ da0 ; db0 = colsum(da0)
        gemm(S_kk, 1, DD, S_aug, HH, 1, S_dW0, HH, nullptr, nullptr, 0, 1.f, 0.f, DD, HH, 1024, 0);
        zero_k<<<8, 256, 0, stream>>>(S_db0, HH);
        colsum_k<<<dim3(HH / 256, 16), 256, 0, stream>>>(S_aug, S_db0, 1024, HH);
        // momentum + weight update
        update_k<<<2048, 256, 0, stream>>>(mem_w0, mom_w0, S_dW0, (long)DD * HH);
        update_k<<<2048, 256, 0, stream>>>(mem_w1, mom_w1, S_sc, (long)HH * DD);
        update_k<<<8, 256, 0, stream>>>(mem_b0, mom_b0, S_db0, HH);
        update_k<<<4, 256, 0, stream>>>(mem_b1, mom_b1, S_db1, DD);
        // mem_out = mem_mlp(new mem, l2norm(y_t @ wq_ctx))
        gemm(S_h, DD, 1, wq_ctx, DD, 1, S_xn, DD, nullptr, nullptr, 0, 1.f, 0.f, 1024, DD, DD, 0);
        l2n_k<<<1024, 256, 0, stream>>>(S_xn, 1.f);
        gemm(S_xn, DD, 1, mem_w0, HH, 1, S_dh, HH, mem_b0, nullptr, 0, 1.f, 0.f, 1024, HH, DD, 1);
        gemm(S_dh, HH, 1, mem_w1, DD, 1, S_mo, DD, mem_b1, nullptr, 0, 1.f, 0.f, 1024, DD, HH, 0);
        // gated combine
        ln_k<<<1024, 256, 0, stream>>>(S_h, gate_g, gate_b, S_gl);
        gemm(S_gl, DD, 1, w_gate, DD, 1, S_gp, DD, nullptr, nullptr, 0, 1.f, 0.f, 1024, DD, DD, 0);
        gate_k<<<1024, 256, 0, stream>>>(S_h, S_gp, S_mo, S_o, (long)1024 * DD);
        // FFN with residual, streamed straight into d_out
        ln_k<<<1024, 256, 0, stream>>>(S_o, n2_g, n2_b, S_gl);
        gemm(S_gl, DD, 1, ffn_w1, FFd, 1, S_kb, FFd, ffn_b1, nullptr, 0, 1.f, 0.f, 1024, FFd, DD, 1);
        for (int b = 0; b < 2; ++b)
            gemm(S_kb + (long)b * CC * FFd, FFd, 1, ffn_w2, DD, 1,
                 out + ((long)b * TT + c * CC) * DD, DD, ffn_b2,
                 S_o + (long)b * CC * DD, DD, 1.f, 1.f, CC, DD, FFd, 0);
    }
}

// Round 2
// 7173.676 us; speedup vs baseline: 2.3441x; 2.3441x over previous
//
#include <hip/hip_runtime.h>

#define DD 1024
#define HH 2048
#define TT 4096
#define CC 512
#define PPc 16
#define SB 1040   // per-batch aug rows
#define KA 1056   // padded attention K (multiple of 32)
#define FFd 4096
#define NCH 8

typedef _Float16 f16x8 __attribute__((ext_vector_type(8)));
typedef float f32x4 __attribute__((ext_vector_type(4)));

typedef const __attribute__((address_space(1))) _Float16* gas_t;
typedef __attribute__((address_space(3))) _Float16* las_t;

__device__ __forceinline__ void async_cp16(const _Float16* g, _Float16* l) {
    __builtin_amdgcn_global_load_lds((gas_t)g, (las_t)l, 16, 0, 0);
}

// C = act(A @ Bt^T + bias); A [M][K] f16 k-fast, Bt [N][K] f16 k-fast. K%32==0.
// act: 0 none, 1 silu, 2 mul-by-dsilu(aux). val = s1*act_v + s2*resid.
// Cf stores (act==1 ? raw : val); Ch stores val; Ct stores val at [n][m].
template<int BM>
__global__ __launch_bounds__(256) void gemm16(
    const _Float16* __restrict__ A, long bsA,
    const _Float16* __restrict__ Bt, long bsB,
    const float* __restrict__ bias,
    const float* __restrict__ resid, long ldr, long bsR,
    const float* __restrict__ aux, long ldx, long bsX,
    float* __restrict__ Cf, long ldc, long bsC,
    _Float16* __restrict__ Ch, long ldh, long bsH,
    _Float16* __restrict__ Ct, long ldt, long bsT,
    float s1, float s2, int M, int N, int K, int act)
{
    constexpr int BN = 128;
    constexpr int WM = BM / 2, WN = BN / 2;
    constexpr int FA = WM / 16, FB = WN / 16;
    __shared__ _Float16 As[BM * 32] __attribute__((aligned(16)));
    __shared__ _Float16 Bs[BN * 32] __attribute__((aligned(16)));
    const int tid = threadIdx.x;
    const int z = blockIdx.z;
    const _Float16* Ab = A + (long)z * bsA;
    const _Float16* Bb = Bt + (long)z * bsB;
    const int m0 = blockIdx.y * BM, n0 = blockIdx.x * BN;
    const int wave = tid >> 6, lane = tid & 63;
    const int wr = wave >> 1, wc = wave & 1;
    const int fr = lane & 15, kq = lane >> 4;
    f32x4 acc[FA][FB] = {};
    const int srow = tid >> 2;
    const int scol = (tid & 3) * 8;
    const _Float16* Arow = Ab + (long)(m0 + srow) * K + scol;
    const _Float16* Brow = Bb + (long)(n0 + srow) * K + scol;
    _Float16* lA = &As[wave * 512];
    _Float16* lB = &Bs[wave * 512];

    for (int k0 = 0; k0 < K; k0 += 32) {
#pragma unroll
        for (int r = 0; r < BM / 64; ++r)
            async_cp16(Arow + (long)r * 64 * K + k0, lA + r * 2048);
#pragma unroll
        for (int r = 0; r < 2; ++r)
            async_cp16(Brow + (long)r * 64 * K + k0, lB + r * 2048);
        __syncthreads();
        f16x8 af[FA], bf[FB];
#pragma unroll
        for (int i = 0; i < FA; ++i)
            af[i] = *(const f16x8*)&As[(wr * WM + i * 16 + fr) * 32 + kq * 8];
#pragma unroll
        for (int j = 0; j < FB; ++j)
            bf[j] = *(const f16x8*)&Bs[(wc * WN + j * 16 + fr) * 32 + kq * 8];
#pragma unroll
        for (int i = 0; i < FA; ++i)
#pragma unroll
            for (int j = 0; j < FB; ++j)
                acc[i][j] = __builtin_amdgcn_mfma_f32_16x16x32_f16(af[i], bf[j], acc[i][j], 0, 0, 0);
        __syncthreads();
    }

#pragma unroll
    for (int i = 0; i < FA; ++i) {
        const int gm0 = m0 + wr * WM + i * 16 + kq * 4;
#pragma unroll
        for (int j = 0; j < FB; ++j) {
            const int gn = n0 + wc * WN + j * 16 + fr;
            if (gn >= N) continue;
            const float bv = bias ? bias[gn] : 0.f;
            float vals[4];
#pragma unroll
            for (int r = 0; r < 4; ++r) {
                const int gm = gm0 + r;
                vals[r] = 0.f;
                if (gm >= M) continue;
                const float raw = acc[i][j][r] + bv;
                float av = raw;
                if (act == 1) av = raw / (1.f + __expf(-raw));
                else if (act == 2) {
                    const float a = aux[(long)z * bsX + (long)gm * ldx + gn];
                    const float s = 1.f / (1.f + __expf(-a));
                    av = raw * (s * (1.f + a * (1.f - s)));
                }
                float v = s1 * av;
                if (resid) v += s2 * resid[(long)z * bsR + (long)gm * ldr + gn];
                vals[r] = v;
                if (Cf) Cf[(long)z * bsC + (long)gm * ldc + gn] = (act == 1) ? raw : v;
                if (Ch) Ch[(long)z * bsH + (long)gm * ldh + gn] = (_Float16)v;
            }
            if (Ct) {
                _Float16* p = Ct + (long)z * bsT + (long)gn * ldt + gm0;
#pragma unroll
                for (int r = 0; r < 4; ++r)
                    if (gm0 + r < M) p[r] = (_Float16)vals[r];
            }
        }
    }
}

// ---- elementwise / rowwise ----
__global__ void cvt_k(const float* __restrict__ in, _Float16* __restrict__ out, long n)
{
    long i = ((long)blockIdx.x * 256 + threadIdx.x) * 4;
    if (i >= n) return;
    const float4 v = *(const float4*)(in + i);
    out[i] = (_Float16)v.x; out[i + 1] = (_Float16)v.y;
    out[i + 2] = (_Float16)v.z; out[i + 3] = (_Float16)v.w;
}

// in fp32 [R][C] -> out f16 [C][R], R,C multiples of 64
__global__ void cvtT_k(const float* __restrict__ in, _Float16* __restrict__ out, int R, int C)
{
    __shared__ _Float16 t[64][65];
    const int c0 = blockIdx.x * 64, r0 = blockIdx.y * 64;
    const int tid = threadIdx.x;
    for (int i = 0; i < 16; ++i) {
        const int lin = i * 256 + tid;
        const int r = lin >> 6, cc = lin & 63;
        t[r][cc] = (_Float16)in[(long)(r0 + r) * C + c0 + cc];
    }
    __syncthreads();
    for (int i = 0; i < 16; ++i) {
        const int lin = i * 256 + tid;
        const int r2 = lin >> 6, c2 = lin & 63;
        out[(long)(c0 + r2) * R + r0 + c2] = t[c2][r2];
    }
}

__global__ void l2n16_k(const float* __restrict__ in, _Float16* __restrict__ out, float scale)
{
    const long row = blockIdx.x;
    const float* p = in + row * DD;
    _Float16* q = out + row * DD;
    const int t = threadIdx.x;
    float e0 = p[t], e1 = p[t + 256], e2 = p[t + 512], e3 = p[t + 768];
    __shared__ float rq[256];
    rq[t] = e0 * e0 + e1 * e1 + e2 * e2 + e3 * e3;
    __syncthreads();
    for (int k = 128; k; k >>= 1) { if (t < k) rq[t] += rq[t + k]; __syncthreads(); }
    const float f = scale / fmaxf(sqrtf(rq[0]), 1e-12f);
    q[t] = (_Float16)(e0 * f); q[t + 256] = (_Float16)(e1 * f);
    q[t + 512] = (_Float16)(e2 * f); q[t + 768] = (_Float16)(e3 * f);
}

__global__ void ln16_k(const float* __restrict__ x, const float* __restrict__ g,
                       const float* __restrict__ b, _Float16* __restrict__ o)
{
    const long row = blockIdx.x;
    const float* p = x + row * DD;
    _Float16* q = o + row * DD;
    const int t = threadIdx.x;
    float e0 = p[t], e1 = p[t + 256], e2 = p[t + 512], e3 = p[t + 768];
    __shared__ float rs[256], rq[256];
    rs[t] = e0 + e1 + e2 + e3;
    rq[t] = e0 * e0 + e1 * e1 + e2 * e2 + e3 * e3;
    __syncthreads();
    for (int k = 128; k; k >>= 1) {
        if (t < k) { rs[t] += rs[t + k]; rq[t] += rq[t + k]; }
        __syncthreads();
    }
    const float mean = rs[0] * (1.f / DD);
    const float inv = rsqrtf(rq[0] * (1.f / DD) - mean * mean + 1e-5f);
    q[t]       = (_Float16)((e0 - mean) * inv * g[t]       + b[t]);
    q[t + 256] = (_Float16)((e1 - mean) * inv * g[t + 256] + b[t + 256]);
    q[t + 512] = (_Float16)((e2 - mean) * inv * g[t + 512] + b[t + 512]);
    q[t + 768] = (_Float16)((e3 - mean) * inv * g[t + 768] + b[t + 768]);
}

// build aug row + LN -> laug f16 [2][SB][D]
__global__ void lnaug_k(const float* __restrict__ x, const float* __restrict__ pers,
                        const float* __restrict__ h, const float* __restrict__ g,
                        const float* __restrict__ b, _Float16* __restrict__ out, int c)
{
    const int row = blockIdx.x;             // 0..2079
    const int bb = row / SB, i = row % SB;
    const float* p;
    if (i < PPc) p = pers + (long)i * DD;
    else if (i < PPc + CC) p = h + (long)(bb * CC + i - PPc) * DD;
    else p = x + (long)(bb * TT + c * CC + (i - PPc - CC)) * DD;
    _Float16* q = out + (long)row * DD;
    const int t = threadIdx.x;
    float e0 = p[t], e1 = p[t + 256], e2 = p[t + 512], e3 = p[t + 768];
    __shared__ float rs[256], rq[256];
    rs[t] = e0 + e1 + e2 + e3;
    rq[t] = e0 * e0 + e1 * e1 + e2 * e2 + e3 * e3;
    __syncthreads();
    for (int k = 128; k; k >>= 1) {
        if (t < k) { rs[t] += rs[t + k]; rq[t] += rq[t + k]; }
        __syncthreads();
    }
    const float mean = rs[0] * (1.f / DD);
    const float inv = rsqrtf(rq[0] * (1.f / DD) - mean * mean + 1e-5f);
    q[t]       = (_Float16)((e0 - mean) * inv * g[t]       + b[t]);
    q[t + 256] = (_Float16)((e1 - mean) * inv * g[t + 256] + b[t + 256]);
    q[t + 512] = (_Float16)((e2 - mean) * inv * g[t + 512] + b[t + 512]);
    q[t + 768] = (_Float16)((e3 - mean) * inv * g[t + 768] + b[t + 768]);
}

// scores f32 [2][512][1040] -> probs f16 [2][512][1056] (cols>=1040 zeroed)
__global__ void softmax16_k(const float* __restrict__ sc, _Float16* __restrict__ pr)
{
    const int blk = blockIdx.x;             // 0..1023
    const int r = blk & 511;
    const int i = PPc + CC + r;             // row index within aug
    const float* p = sc + (long)blk * SB;
    _Float16* q = pr + (long)blk * KA;
    const int t = threadIdx.x;
    __shared__ float red[256];
    float mx = -3.0e38f;
    for (int j = t; j < SB; j += 256)
        if (j <= i) mx = fmaxf(mx, p[j]);
    red[t] = mx; __syncthreads();
    for (int k = 128; k; k >>= 1) { if (t < k) red[t] = fmaxf(red[t], red[t + k]); __syncthreads(); }
    mx = red[0]; __syncthreads();
    float sum = 0.f;
    for (int j = t; j < SB; j += 256) {
        float e = (j <= i) ? __expf(p[j] - mx) : 0.f;
        sum += e;
    }
    red[t] = sum; __syncthreads();
    for (int k = 128; k; k >>= 1) { if (t < k) red[t] += red[t + k]; __syncthreads(); }
    const float inv = 1.f / red[0];
    for (int j = t; j < KA; j += 256) {
        float e = 0.f;
        if (j < SB && j <= i) e = __expf(p[j] - mx) * inv;
        q[j] = (_Float16)e;
    }
}

__global__ void gate_k(const float* __restrict__ yt, const float* __restrict__ gp,
                       const float* __restrict__ mo, float* __restrict__ o, long n)
{
    long i = (long)blockIdx.x * 256 + threadIdx.x;
    if (i >= n) return;
    const float s = 1.f / (1.f + __expf(-gp[i]));
    o[i] = yt[i] * s + mo[i] * (1.f - s);
}

__global__ void colsum16_k(const _Float16* __restrict__ X, float* __restrict__ out, int M, int N)
{
    const int col = blockIdx.x * 256 + threadIdx.x;
    const int per = (M + gridDim.y - 1) / gridDim.y;
    const int r0 = blockIdx.y * per;
    int r1 = r0 + per; if (r1 > M) r1 = M;
    float s = 0.f;
    for (int r = r0; r < r1; ++r) s += (float)X[(long)r * N + col];
    atomicAdd(&out[col], s);
}

__global__ void rowsum16_k(const _Float16* __restrict__ X, float* __restrict__ out)
{
    const long row = blockIdx.x;
    const _Float16* p = X + row * 1024;
    const int t = threadIdx.x;
    __shared__ float red[256];
    red[t] = (float)p[t] + (float)p[t + 256] + (float)p[t + 512] + (float)p[t + 768];
    __syncthreads();
    for (int k = 128; k; k >>= 1) { if (t < k) red[t] += red[t + k]; __syncthreads(); }
    if (t == 0) out[row] = red[0];
}

__global__ void zero_k(float* __restrict__ p, long n)
{
    long i = (long)blockIdx.x * 256 + threadIdx.x;
    const long st = (long)gridDim.x * 256;
    for (; i < n; i += st) p[i] = 0.f;
}

__global__ void update_k(float* __restrict__ mem, float* __restrict__ mom,
                         const float* __restrict__ g, long n)
{
    long i = (long)blockIdx.x * 256 + threadIdx.x;
    const long st = (long)gridDim.x * 256;
    for (; i < n; i += st) {
        const float m = 0.9f * mom[i] + g[i];
        mom[i] = m;
        mem[i] = 0.99f * mem[i] - 0.01f * m;
    }
}

extern "C" void kernel_launch(void* const* d_in, const int* in_sizes, int n_in,
                              void* d_out, int out_size, void* d_ws, size_t ws_size,
                              hipStream_t stream)
{
    const float* x          = (const float*)d_in[0];
    const float* wq_ctx     = (const float*)d_in[1];
    const float* wq         = (const float*)d_in[2];
    const float* wk         = (const float*)d_in[3];
    const float* wv         = (const float*)d_in[4];
    const float* w_attn_out = (const float*)d_in[5];
    const float* w_gate     = (const float*)d_in[6];
    const float* gate_g     = (const float*)d_in[7];
    const float* gate_b     = (const float*)d_in[8];
    const float* n1_g       = (const float*)d_in[9];
    const float* n1_b       = (const float*)d_in[10];
    const float* n2_g       = (const float*)d_in[11];
    const float* n2_b       = (const float*)d_in[12];
    const float* ffn_w1     = (const float*)d_in[13];
    const float* ffn_b1     = (const float*)d_in[14];
    const float* ffn_w2     = (const float*)d_in[15];
    const float* ffn_b2     = (const float*)d_in[16];
    const float* pers       = (const float*)d_in[17];
    const float* mem_w0_in  = (const float*)d_in[18];
    const float* mem_b0_in  = (const float*)d_in[19];
    const float* mem_w1_in  = (const float*)d_in[20];
    const float* mem_b1_in  = (const float*)d_in[21];
    const float* mem_wk     = (const float*)d_in[22];
    const float* mem_wv     = (const float*)d_in[23];
    float* out = (float*)d_out;
    (void)in_sizes; (void)n_in; (void)out_size; (void)ws_size;

    char* cur = (char*)d_ws;
    auto allocF = [&](size_t n) { float* p = (float*)cur; cur += n * 4; return p; };
    auto allocH = [&](size_t n) { _Float16* p = (_Float16*)cur; cur += n * 2; return p; };

    // fp32 persistent + scratch
    float* mw0  = allocF((size_t)DD * HH);
    float* mw1  = allocF((size_t)HH * DD);
    float* mb0  = allocF(HH);
    float* mb1  = allocF(DD);
    float* mom  = allocF((size_t)DD * HH * 2 + HH + DD);
    float* mom_w0 = mom, *mom_w1 = mom + (size_t)DD * HH;
    float* mom_b0 = mom_w1 + (size_t)HH * DD, *mom_b1 = mom_b0 + HH;
    float* F32A = allocF((size_t)2080 * DD);
    float* F32B = allocF((size_t)1024 * DD);
    float* F32C = allocF((size_t)1024 * HH);
    float* YTF  = allocF((size_t)1024 * DD);
    float* OF   = allocF((size_t)1024 * DD);
    float* DW1F = allocF((size_t)HH * DD);
    float* DW0F = allocF((size_t)DD * HH);
    float* db0  = allocF(HH);
    float* db1  = allocF(DD);

    // f16 buffers
    _Float16* x16    = allocH((size_t)2 * TT * DD);
    _Float16* wqcT   = allocH((size_t)DD * DD);
    _Float16* wqT    = allocH((size_t)DD * DD);
    _Float16* wkT    = allocH((size_t)DD * DD);
    _Float16* wvT    = allocH((size_t)DD * DD);
    _Float16* waoT   = allocH((size_t)DD * DD);
    _Float16* wgT    = allocH((size_t)DD * DD);
    _Float16* wkmT   = allocH((size_t)DD * DD);
    _Float16* wvmT   = allocH((size_t)DD * DD);
    _Float16* f1T    = allocH((size_t)FFd * DD);
    _Float16* f2T    = allocH((size_t)DD * FFd);
    _Float16* w0T    = allocH((size_t)HH * DD);
    _Float16* w1T    = allocH((size_t)DD * HH);
    _Float16* w1p    = allocH((size_t)HH * DD);
    _Float16* xn16   = allocH((size_t)1024 * DD);
    _Float16* h116   = allocH((size_t)1024 * HH);
    _Float16* laug16 = allocH((size_t)2208 * DD);   // 2*SB + 128 slack rows
    _Float16* q16    = allocH((size_t)1024 * DD);
    _Float16* k16    = allocH((size_t)2208 * DD);   // + slack
    _Float16* vT16   = allocH((size_t)2 * DD * KA);
    _Float16* pr16   = allocH((size_t)2 * 512 * KA);
    _Float16* ao16   = allocH((size_t)1024 * DD);
    _Float16* yt16   = allocH((size_t)1024 * DD);
    _Float16* kk16   = allocH((size_t)1024 * DD);
    _Float16* kkT16  = allocH((size_t)DD * 1024);
    _Float16* hs16   = allocH((size_t)1024 * HH);
    _Float16* hsT16  = allocH((size_t)HH * 1024);
    _Float16* r16    = allocH((size_t)1024 * DD);
    _Float16* rT16   = allocH((size_t)DD * 1024);
    _Float16* da0T   = allocH((size_t)HH * 1024);
    _Float16* qm16   = allocH((size_t)1024 * DD);
    _Float16* a216   = allocH((size_t)1024 * HH);
    _Float16* gl16   = allocH((size_t)1024 * DD);
    _Float16* h216   = allocH((size_t)1024 * DD);
    _Float16* f116   = allocH((size_t)1024 * FFd);

    auto G = [&](int bm, const _Float16* A, long bsA, const _Float16* Bt, long bsB,
                 const float* bias, const float* resid, long ldr, long bsR,
                 const float* aux, long ldx, long bsX,
                 float* Cf, long ldc, long bsC, _Float16* Ch, long ldh, long bsH,
                 _Float16* Ct, long ldt, long bsT,
                 float s1, float s2, int M, int N, int K, int act, int nz) {
        dim3 g((N + 127) / 128, (M + bm - 1) / bm, nz);
        if (bm == 128)
            gemm16<128><<<g, 256, 0, stream>>>(A, bsA, Bt, bsB, bias, resid, ldr, bsR,
                aux, ldx, bsX, Cf, ldc, bsC, Ch, ldh, bsH, Ct, ldt, bsT, s1, s2, M, N, K, act);
        else
            gemm16<64><<<g, 256, 0, stream>>>(A, bsA, Bt, bsB, bias, resid, ldr, bsR,
                aux, ldx, bsX, Cf, ldc, bsC, Ch, ldh, bsH, Ct, ldt, bsT, s1, s2, M, N, K, act);
    };
    const float* nf = nullptr; float* nF = nullptr; _Float16* nH = nullptr;

    // ---- per-call init ----
    hipMemcpyAsync(mw0, mem_w0_in, sizeof(float) * DD * HH, hipMemcpyDeviceToDevice, stream);
    hipMemcpyAsync(mw1, mem_w1_in, sizeof(float) * HH * DD, hipMemcpyDeviceToDevice, stream);
    hipMemcpyAsync(mb0, mem_b0_in, sizeof(float) * HH, hipMemcpyDeviceToDevice, stream);
    hipMemcpyAsync(mb1, mem_b1_in, sizeof(float) * DD, hipMemcpyDeviceToDevice, stream);
    zero_k<<<4096, 256, 0, stream>>>(mom, (long)DD * HH * 2 + HH + DD);
    cvt_k<<<(2 * TT * DD) / 1024, 256, 0, stream>>>(x, x16, (long)2 * TT * DD);
    auto T64 = [&](const float* in, _Float16* o, int R, int C) {
        cvtT_k<<<dim3(C / 64, R / 64), 256, 0, stream>>>(in, o, R, C);
    };
    T64(wq_ctx, wqcT, DD, DD); T64(wq, wqT, DD, DD); T64(wk, wkT, DD, DD);
    T64(wv, wvT, DD, DD); T64(w_attn_out, waoT, DD, DD); T64(w_gate, wgT, DD, DD);
    T64(mem_wk, wkmT, DD, DD); T64(mem_wv, wvmT, DD, DD);
    T64(ffn_w1, f1T, DD, FFd); T64(ffn_w2, f2T, FFd, DD);
    T64(mem_w0_in, w0T, DD, HH); T64(mem_w1_in, w1T, HH, DD);
    cvt_k<<<(HH * DD) / 1024, 256, 0, stream>>>(mem_w1_in, w1p, (long)HH * DD);

    for (int c = 0; c < NCH; ++c) {
        // xn = l2norm(seg @ wq_ctx)
        G(64, x16 + (long)c * CC * DD, (long)TT * DD, wqcT, 0, nf, nf, 0, 0, nf, 0, 0,
          F32A, DD, (long)CC * DD, nH, 0, 0, nH, 0, 0, 1.f, 0.f, CC, DD, DD, 0, 2);
        l2n16_k<<<1024, 256, 0, stream>>>(F32A, xn16, 1.f);
        // h = mem_mlp(mem, xn)
        G(128, xn16, 0, w0T, 0, mb0, nf, 0, 0, nf, 0, 0, nF, 0, 0, h116, HH, 0, nH, 0, 0,
          1.f, 0.f, 1024, HH, DD, 1, 1);
        G(64, h116, 0, w1T, 0, mb1, nf, 0, 0, nf, 0, 0, F32B, DD, 0, nH, 0, 0, nH, 0, 0,
          1.f, 0.f, 1024, DD, HH, 0, 1);
        // aug build + LN1 -> laug f16
        lnaug_k<<<2 * SB, 256, 0, stream>>>(x, pers, F32B, n1_g, n1_b, laug16, c);
        // q (only last 512 rows per batch), k, v
        G(64, laug16 + (long)(PPc + CC) * DD, (long)SB * DD, wqT, 0, nf, nf, 0, 0, nf, 0, 0,
          F32A, DD, (long)512 * DD, nH, 0, 0, nH, 0, 0, 1.f, 0.f, 512, DD, DD, 0, 2);
        l2n16_k<<<1024, 256, 0, stream>>>(F32A, q16, 32.f);
        G(64, laug16, 0, wkT, 0, nf, nf, 0, 0, nf, 0, 0,
          F32A, DD, 0, nH, 0, 0, nH, 0, 0, 1.f, 0.f, 2 * SB, DD, DD, 0, 1);
        l2n16_k<<<2 * SB, 256, 0, stream>>>(F32A, k16, 1.f);
        G(64, laug16, (long)SB * DD, wvT, 0, nf, nf, 0, 0, nf, 0, 0,
          nF, 0, 0, nH, 0, 0, vT16, KA, (long)DD * KA, 1.f, 0.f, SB, DD, DD, 0, 2);
        // scores -> softmax -> probs
        G(64, q16, (long)512 * DD, k16, (long)SB * DD, nf, nf, 0, 0, nf, 0, 0,
          F32C, SB, (long)512 * SB, nH, 0, 0, nH, 0, 0, 1.f, 0.f, 512, SB, DD, 0, 2);
        softmax16_k<<<1024, 256, 0, stream>>>(F32C, pr16);
        // attn = probs @ v  (K padded to 1056)
        G(64, pr16, (long)512 * KA, vT16, (long)DD * KA, nf, nf, 0, 0, nf, 0, 0,
          nF, 0, 0, ao16, DD, (long)512 * DD, nH, 0, 0, 1.f, 0.f, 512, DD, KA, 0, 2);
        // y_t = seg + attn @ w_attn_out
        G(64, ao16, (long)512 * DD, waoT, 0, nf, x + (long)c * CC * DD, DD, (long)TT * DD,
          nf, 0, 0, YTF, DD, (long)512 * DD, yt16, DD, (long)512 * DD, nH, 0, 0,
          1.f, 1.f, 512, DD, DD, 0, 2);
        // kk (dual f16 + f16T), vv
        G(64, yt16, 0, wkmT, 0, nf, nf, 0, 0, nf, 0, 0, nF, 0, 0,
          kk16, DD, 0, kkT16, 1024, 0, 1.f, 0.f, 1024, DD, DD, 0, 1);
        G(64, yt16, 0, wvmT, 0, nf, nf, 0, 0, nf, 0, 0, F32B, DD, 0, nH, 0, 0, nH, 0, 0,
          1.f, 0.f, 1024, DD, DD, 0, 1);
        // a0 = kk@w0+b0 (f32 raw) ; hs = silu(a0) f16 + f16T
        G(128, kk16, 0, w0T, 0, mb0, nf, 0, 0, nf, 0, 0, F32C, HH, 0,
          hs16, HH, 0, hsT16, 1024, 0, 1.f, 0.f, 1024, HH, DD, 1, 1);
        // r = (hs@w1 + b1 - vv)/1024, f16 + f16T
        G(64, hs16, 0, w1T, 0, mb1, F32B, DD, 0, nf, 0, 0, nF, 0, 0,
          r16, DD, 0, rT16, 1024, 0, 1.f / 1024.f, -1.f / 1024.f, 1024, DD, HH, 0, 1);
        // dW1 = hsT @ rT^T ; db1 = colsum(r)
        G(128, hsT16, 0, rT16, 0, nf, nf, 0, 0, nf, 0, 0, DW1F, DD, 0, nH, 0, 0, nH, 0, 0,
          1.f, 0.f, HH, DD, 1024, 0, 1);
        zero_k<<<4, 256, 0, stream>>>(db1, DD);
        colsum16_k<<<dim3(4, 16), 256, 0, stream>>>(r16, db1, 1024, DD);
        // da0T = (r @ w1) * dsilu(a0), written transposed
        G(128, r16, 0, w1p, 0, nf, nf, 0, 0, F32C, HH, 0, nF, 0, 0, nH, 0, 0,
          da0T, 1024, 0, 1.f, 0.f, 1024, HH, DD, 2, 1);
        rowsum16_k<<<HH, 256, 0, stream>>>(da0T, db0);
        // dW0 = kkT @ da0T^T
        G(128, kkT16, 0, da0T, 0, nf, nf, 0, 0, nf, 0, 0, DW0F, HH, 0, nH, 0, 0, nH, 0, 0,
          1.f, 0.f, DD, HH, 1024, 0, 1);
        // momentum + weight update, re-cast f16 weights
        update_k<<<2048, 256, 0, stream>>>(mw0, mom_w0, DW0F, (long)DD * HH);
        update_k<<<2048, 256, 0, stream>>>(mw1, mom_w1, DW1F, (long)HH * DD);
        update_k<<<8, 256, 0, stream>>>(mb0, mom_b0, db0, HH);
        update_k<<<4, 256, 0, stream>>>(mb1, mom_b1, db1, DD);
        T64(mw0, w0T, DD, HH);
        T64(mw1, w1T, HH, DD);
        cvt_k<<<(HH * DD) / 1024, 256, 0, stream>>>(mw1, w1p, (long)HH * DD);
        // mem_out = mem_mlp(new mem, l2norm(y_t @ wq_ctx))
        G(64, yt16, 0, wqcT, 0, nf, nf, 0, 0, nf, 0, 0, F32A, DD, 0, nH, 0, 0, nH, 0, 0,
          1.f, 0.f, 1024, DD, DD, 0, 1);
        l2n16_k<<<1024, 256, 0, stream>>>(F32A, qm16, 1.f);
        G(128, qm16, 0, w0T, 0, mb0, nf, 0, 0, nf, 0, 0, nF, 0, 0, a216, HH, 0, nH, 0, 0,
          1.f, 0.f, 1024, HH, DD, 1, 1);
        G(64, a216, 0, w1T, 0, mb1, nf, 0, 0, nf, 0, 0, F32B, DD, 0, nH, 0, 0, nH, 0, 0,
          1.f, 0.f, 1024, DD, HH, 0, 1);
        // gate
        ln16_k<<<1024, 256, 0, stream>>>(YTF, gate_g, gate_b, gl16);
        G(64, gl16, 0, wgT, 0, nf, nf, 0, 0, nf, 0, 0, F32A, DD, 0, nH, 0, 0, nH, 0, 0,
          1.f, 0.f, 1024, DD, DD, 0, 1);
        gate_k<<<4096, 256, 0, stream>>>(YTF, F32A, F32B, OF, (long)1024 * DD);
        // FFN
        ln16_k<<<1024, 256, 0, stream>>>(OF, n2_g, n2_b, h216);
        G(128, h216, 0, f1T, 0, ffn_b1, nf, 0, 0, nf, 0, 0, nF, 0, 0, f116, FFd, 0, nH, 0, 0,
          1.f, 0.f, 1024, FFd, DD, 1, 1);
        G(64, f116, (long)512 * FFd, f2T, 0, ffn_b2, OF, DD, (long)512 * DD, nf, 0, 0,
          out + (long)c * CC * DD, DD, (long)TT * DD, nH, 0, 0, nH, 0, 0,
          1.f, 1.f, 512, DD, FFd, 0, 2);
    }
}

// Round 3
// 5710.443 us; speedup vs baseline: 2.9447x; 1.2562x over previous
//
#include <hip/hip_runtime.h>

#define DD 1024
#define HH 2048
#define TT 4096
#define CC 512
#define PPc 16
#define SB 1040   // per-batch aug rows
#define KA 1056   // padded attention K (multiple of 32)
#define FFd 4096
#define NCH 8

typedef _Float16 f16x8 __attribute__((ext_vector_type(8)));
typedef float f32x4 __attribute__((ext_vector_type(4)));

typedef const __attribute__((address_space(1))) _Float16* gas_t;
typedef __attribute__((address_space(3))) _Float16* las_t;

__device__ __forceinline__ void async_cp16(const _Float16* g, _Float16* l) {
    __builtin_amdgcn_global_load_lds((gas_t)g, (las_t)l, 16, 0, 0);
}

struct GP {
    const _Float16* A; long bsA;
    const _Float16* Bt; long bsB;
    const float* bias;
    const float* resid; long ldr, bsR;
    const float* aux;   long ldx, bsX;
    float* Cf; long ldc, bsC;
    _Float16* Ch; long ldh, bsH;
    _Float16* Ct; long ldt, bsT;
    float* Mom;
    float* Cf2;
    float s1, s2;
    int M, N, K, act;
};

// acts: 0 plain, 1 silu (Cf<-raw, Ch/Ct<-silu), 2 mul-by-dsilu(aux),
//       3 momentum weight update (Cf=master w, Mom=momentum, Ch/Ct new f16 w),
//       4 kvq routing (n<1024 -> Ch+Ct, <2048 -> Cf, else Cf2; all ld 1024)
template<int BM>
__global__ __launch_bounds__(256) void gemm16(GP g)
{
    constexpr int BN = 128;
    constexpr int WM = BM / 2, WN = BN / 2;
    constexpr int FA = WM / 16, FB = WN / 16;
    __shared__ _Float16 As[2 * BM * 32] __attribute__((aligned(16)));
    __shared__ _Float16 Bs[2 * BN * 32] __attribute__((aligned(16)));
    const int tid = threadIdx.x;
    const int z = blockIdx.z;
    const int K = g.K;
    const _Float16* Ab = g.A + (long)z * g.bsA;
    const _Float16* Bb = g.Bt + (long)z * g.bsB;
    const int m0 = blockIdx.y * BM, n0 = blockIdx.x * BN;
    const int wave = tid >> 6, lane = tid & 63;
    const int wr = wave >> 1, wc = wave & 1;
    const int fr = lane & 15, kq = lane >> 4;
    f32x4 acc[FA][FB] = {};
    const int srow = tid >> 2;
    const int scol = (tid & 3) * 8;
    const _Float16* Arow = Ab + (long)(m0 + srow) * K + scol;
    const _Float16* Brow = Bb + (long)(n0 + srow) * K + scol;

    auto stage = [&](int pp, int kk) {
        _Float16* lA = &As[pp * BM * 32 + wave * 512];
        _Float16* lB = &Bs[pp * BN * 32 + wave * 512];
#pragma unroll
        for (int r = 0; r < BM / 64; ++r)
            async_cp16(Arow + (long)r * 64 * K + kk, lA + r * 2048);
#pragma unroll
        for (int r = 0; r < 2; ++r)
            async_cp16(Brow + (long)r * 64 * K + kk, lB + r * 2048);
    };

    stage(0, 0);
    int p = 0;
    for (int k0 = 0; k0 < K; k0 += 32) {
        __syncthreads();
        if (k0 + 32 < K) stage(p ^ 1, k0 + 32);
        f16x8 af[FA], bf[FB];
#pragma unroll
        for (int i = 0; i < FA; ++i)
            af[i] = *(const f16x8*)&As[p * BM * 32 + (wr * WM + i * 16 + fr) * 32 + kq * 8];
#pragma unroll
        for (int j = 0; j < FB; ++j)
            bf[j] = *(const f16x8*)&Bs[p * BN * 32 + (wc * WN + j * 16 + fr) * 32 + kq * 8];
#pragma unroll
        for (int i = 0; i < FA; ++i)
#pragma unroll
            for (int j = 0; j < FB; ++j)
                acc[i][j] = __builtin_amdgcn_mfma_f32_16x16x32_f16(af[i], bf[j], acc[i][j], 0, 0, 0);
        p ^= 1;
    }

#pragma unroll
    for (int i = 0; i < FA; ++i) {
        const int gm0 = m0 + wr * WM + i * 16 + kq * 4;
#pragma unroll
        for (int j = 0; j < FB; ++j) {
            const int gn = n0 + wc * WN + j * 16 + fr;
            if (gn >= g.N) continue;
            if (g.act == 3) {
#pragma unroll
                for (int r = 0; r < 4; ++r) {
                    const int gm = gm0 + r;
                    if (gm >= g.M) continue;
                    const long idx = (long)gm * g.ldc + gn;
                    const float m = 0.9f * g.Mom[idx] + acc[i][j][r];
                    g.Mom[idx] = m;
                    const float v = 0.99f * g.Cf[idx] - 0.01f * m;
                    g.Cf[idx] = v;
                    if (g.Ch) g.Ch[(long)gm * g.ldh + gn] = (_Float16)v;
                    if (g.Ct) g.Ct[(long)gn * g.ldt + gm] = (_Float16)v;
                }
            } else if (g.act == 4) {
                const int seg = gn >> 10, gl = gn & 1023;
#pragma unroll
                for (int r = 0; r < 4; ++r) {
                    const int gm = gm0 + r;
                    if (gm >= g.M) continue;
                    const float v = acc[i][j][r];
                    if (seg == 0) {
                        g.Ch[(long)gm * 1024 + gl] = (_Float16)v;
                        g.Ct[(long)gl * 1024 + gm] = (_Float16)v;
                    } else if (seg == 1) g.Cf[(long)gm * 1024 + gl] = v;
                    else g.Cf2[(long)gm * 1024 + gl] = v;
                }
            } else {
                const float bv = g.bias ? g.bias[gn] : 0.f;
                float vals[4];
#pragma unroll
                for (int r = 0; r < 4; ++r) {
                    const int gm = gm0 + r;
                    vals[r] = 0.f;
                    if (gm >= g.M) continue;
                    const float raw = acc[i][j][r] + bv;
                    float av = raw;
                    if (g.act == 1) av = raw / (1.f + __expf(-raw));
                    else if (g.act == 2) {
                        const float a = g.aux[(long)z * g.bsX + (long)gm * g.ldx + gn];
                        const float s = 1.f / (1.f + __expf(-a));
                        av = raw * (s * (1.f + a * (1.f - s)));
                    }
                    float v = g.s1 * av;
                    if (g.resid) v += g.s2 * g.resid[(long)z * g.bsR + (long)gm * g.ldr + gn];
                    vals[r] = v;
                    if (g.Cf) g.Cf[(long)z * g.bsC + (long)gm * g.ldc + gn] = (g.act == 1) ? raw : v;
                    if (g.Ch) g.Ch[(long)z * g.bsH + (long)gm * g.ldh + gn] = (_Float16)v;
                }
                if (g.Ct) {
                    _Float16* pt = g.Ct + (long)z * g.bsT + (long)gn * g.ldt + gm0;
#pragma unroll
                    for (int r = 0; r < 4; ++r)
                        if (gm0 + r < g.M) pt[r] = (_Float16)vals[r];
                }
            }
        }
    }
}

// ---- elementwise / rowwise ----
__global__ void cvt_k(const float* __restrict__ in, _Float16* __restrict__ out, long n)
{
    long i = ((long)blockIdx.x * 256 + threadIdx.x) * 4;
    if (i >= n) return;
    const float4 v = *(const float4*)(in + i);
    out[i] = (_Float16)v.x; out[i + 1] = (_Float16)v.y;
    out[i + 2] = (_Float16)v.z; out[i + 3] = (_Float16)v.w;
}

__global__ void cvtT_k(const float* __restrict__ in, _Float16* __restrict__ out, int R, int C)
{
    __shared__ _Float16 t[64][65];
    const int c0 = blockIdx.x * 64, r0 = blockIdx.y * 64;
    const int tid = threadIdx.x;
    for (int i = 0; i < 16; ++i) {
        const int lin = i * 256 + tid;
        const int r = lin >> 6, cc = lin & 63;
        t[r][cc] = (_Float16)in[(long)(r0 + r) * C + c0 + cc];
    }
    __syncthreads();
    for (int i = 0; i < 16; ++i) {
        const int lin = i * 256 + tid;
        const int r2 = lin >> 6, c2 = lin & 63;
        out[(long)(c0 + r2) * R + r0 + c2] = t[c2][r2];
    }
}

// l2norm of a 1024-float contiguous row (row stride ld) -> f16
__global__ void l2n16s_k(const float* __restrict__ in, long ld,
                         _Float16* __restrict__ out, float scale)
{
    const long row = blockIdx.x;
    const float* p = in + row * ld;
    _Float16* q = out + row * DD;
    const int t = threadIdx.x;
    float e0 = p[t], e1 = p[t + 256], e2 = p[t + 512], e3 = p[t + 768];
    __shared__ float rq[256];
    rq[t] = e0 * e0 + e1 * e1 + e2 * e2 + e3 * e3;
    __syncthreads();
    for (int k = 128; k; k >>= 1) { if (t < k) rq[t] += rq[t + k]; __syncthreads(); }
    const float f = scale / fmaxf(sqrtf(rq[0]), 1e-12f);
    q[t] = (_Float16)(e0 * f); q[t + 256] = (_Float16)(e1 * f);
    q[t + 512] = (_Float16)(e2 * f); q[t + 768] = (_Float16)(e3 * f);
}

// q rows: blk = b*512 + r -> src row b*SB + P + C + r of F32QK (ld 2048, cols 0..1023)
__global__ void l2nq_k(const float* __restrict__ in, _Float16* __restrict__ out)
{
    const int blk = blockIdx.x;
    const int b = blk >> 9, r = blk & 511;
    const float* p = in + (long)(b * SB + PPc + CC + r) * 2048;
    _Float16* q = out + (long)blk * DD;
    const int t = threadIdx.x;
    float e0 = p[t], e1 = p[t + 256], e2 = p[t + 512], e3 = p[t + 768];
    __shared__ float rq[256];
    rq[t] = e0 * e0 + e1 * e1 + e2 * e2 + e3 * e3;
    __syncthreads();
    for (int k = 128; k; k >>= 1) { if (t < k) rq[t] += rq[t + k]; __syncthreads(); }
    const float f = 32.f / fmaxf(sqrtf(rq[0]), 1e-12f);
    q[t] = (_Float16)(e0 * f); q[t + 256] = (_Float16)(e1 * f);
    q[t + 512] = (_Float16)(e2 * f); q[t + 768] = (_Float16)(e3 * f);
}

__global__ void ln16_k(const float* __restrict__ x, const float* __restrict__ g,
                       const float* __restrict__ b, _Float16* __restrict__ o)
{
    const long row = blockIdx.x;
    const float* p = x + row * DD;
    _Float16* q = o + row * DD;
    const int t = threadIdx.x;
    float e0 = p[t], e1 = p[t + 256], e2 = p[t + 512], e3 = p[t + 768];
    __shared__ float rs[256], rq[256];
    rs[t] = e0 + e1 + e2 + e3;
    rq[t] = e0 * e0 + e1 * e1 + e2 * e2 + e3 * e3;
    __syncthreads();
    for (int k = 128; k; k >>= 1) {
        if (t < k) { rs[t] += rs[t + k]; rq[t] += rq[t + k]; }
        __syncthreads();
    }
    const float mean = rs[0] * (1.f / DD);
    const float inv = rsqrtf(rq[0] * (1.f / DD) - mean * mean + 1e-5f);
    q[t]       = (_Float16)((e0 - mean) * inv * g[t]       + b[t]);
    q[t + 256] = (_Float16)((e1 - mean) * inv * g[t + 256] + b[t + 256]);
    q[t + 512] = (_Float16)((e2 - mean) * inv * g[t + 512] + b[t + 512]);
    q[t + 768] = (_Float16)((e3 - mean) * inv * g[t + 768] + b[t + 768]);
}

__global__ void lnaug_k(const float* __restrict__ x, const float* __restrict__ pers,
                        const float* __restrict__ h, const float* __restrict__ g,
                        const float* __restrict__ b, _Float16* __restrict__ out, int c)
{
    const int row = blockIdx.x;             // 0..2079
    const int bb = row / SB, i = row % SB;
    const float* p;
    if (i < PPc) p = pers + (long)i * DD;
    else if (i < PPc + CC) p = h + (long)(bb * CC + i - PPc) * DD;
    else p = x + (long)(bb * TT + c * CC + (i - PPc - CC)) * DD;
    _Float16* q = out + (long)row * DD;
    const int t = threadIdx.x;
    float e0 = p[t], e1 = p[t + 256], e2 = p[t + 512], e3 = p[t + 768];
    __shared__ float rs[256], rq[256];
    rs[t] = e0 + e1 + e2 + e3;
    rq[t] = e0 * e0 + e1 * e1 + e2 * e2 + e3 * e3;
    __syncthreads();
    for (int k = 128; k; k >>= 1) {
        if (t < k) { rs[t] += rs[t + k]; rq[t] += rq[t + k]; }
        __syncthreads();
    }
    const float mean = rs[0] * (1.f / DD);
    const float inv = rsqrtf(rq[0] * (1.f / DD) - mean * mean + 1e-5f);
    q[t]       = (_Float16)((e0 - mean) * inv * g[t]       + b[t]);
    q[t + 256] = (_Float16)((e1 - mean) * inv * g[t + 256] + b[t + 256]);
    q[t + 512] = (_Float16)((e2 - mean) * inv * g[t + 512] + b[t + 512]);
    q[t + 768] = (_Float16)((e3 - mean) * inv * g[t + 768] + b[t + 768]);
}

__global__ void softmax16_k(const float* __restrict__ sc, _Float16* __restrict__ pr)
{
    const int blk = blockIdx.x;             // 0..1023
    const int r = blk & 511;
    const int i = PPc + CC + r;
    const float* p = sc + (long)blk * SB;
    _Float16* q = pr + (long)blk * KA;
    const int t = threadIdx.x;
    __shared__ float red[256];
    float mx = -3.0e38f;
    for (int j = t; j < SB; j += 256)
        if (j <= i) mx = fmaxf(mx, p[j]);
    red[t] = mx; __syncthreads();
    for (int k = 128; k; k >>= 1) { if (t < k) red[t] = fmaxf(red[t], red[t + k]); __syncthreads(); }
    mx = red[0]; __syncthreads();
    float sum = 0.f;
    for (int j = t; j < SB; j += 256)
        if (j <= i) sum += __expf(p[j] - mx);
    red[t] = sum; __syncthreads();
    for (int k = 128; k; k >>= 1) { if (t < k) red[t] += red[t + k]; __syncthreads(); }
    const float inv = 1.f / red[0];
    for (int j = t; j < KA; j += 256) {
        float e = 0.f;
        if (j < SB && j <= i) e = __expf(p[j] - mx) * inv;
        q[j] = (_Float16)e;
    }
}

// o = yt*sig(gp) + mo*(1-sig(gp)); OF <- o; o16 <- LN(o, g, b)
__global__ void gateln2_k(const float* __restrict__ yt, const float* __restrict__ gp,
                          const float* __restrict__ mo, const float* __restrict__ g,
                          const float* __restrict__ b, float* __restrict__ OF,
                          _Float16* __restrict__ o16)
{
    const long row = blockIdx.x;
    const int t = threadIdx.x;
    float e[4];
    __shared__ float rs[256], rq[256];
    float ssum = 0.f, qsum = 0.f;
#pragma unroll
    for (int k = 0; k < 4; ++k) {
        const long idx = row * DD + t + k * 256;
        const float s = 1.f / (1.f + __expf(-gp[idx]));
        e[k] = yt[idx] * s + mo[idx] * (1.f - s);
        OF[idx] = e[k];
        ssum += e[k]; qsum += e[k] * e[k];
    }
    rs[t] = ssum; rq[t] = qsum;
    __syncthreads();
    for (int k = 128; k; k >>= 1) {
        if (t < k) { rs[t] += rs[t + k]; rq[t] += rq[t + k]; }
        __syncthreads();
    }
    const float mean = rs[0] * (1.f / DD);
    const float inv = rsqrtf(rq[0] * (1.f / DD) - mean * mean + 1e-5f);
#pragma unroll
    for (int k = 0; k < 4; ++k) {
        const int cc = t + k * 256;
        o16[row * DD + cc] = (_Float16)((e[k] - mean) * inv * g[cc] + b[cc]);
    }
}

__global__ void rowsum16_k(const _Float16* __restrict__ X, float* __restrict__ out)
{
    const long row = blockIdx.x;
    const _Float16* p = X + row * 1024;
    const int t = threadIdx.x;
    __shared__ float red[256];
    red[t] = (float)p[t] + (float)p[t + 256] + (float)p[t + 512] + (float)p[t + 768];
    __syncthreads();
    for (int k = 128; k; k >>= 1) { if (t < k) red[t] += red[t + k]; __syncthreads(); }
    if (t == 0) out[row] = red[0];
}

__global__ void biasup_k(float* __restrict__ mb0, float* __restrict__ mob0,
                         const float* __restrict__ db0,
                         float* __restrict__ mb1, float* __restrict__ mob1,
                         const float* __restrict__ db1)
{
    const int i = blockIdx.x * 256 + threadIdx.x;
    if (i < HH) {
        const float m = 0.9f * mob0[i] + db0[i];
        mob0[i] = m;
        mb0[i] = 0.99f * mb0[i] - 0.01f * m;
    } else {
        const int j = i - HH;
        if (j < DD) {
            const float m = 0.9f * mob1[j] + db1[j];
            mob1[j] = m;
            mb1[j] = 0.99f * mb1[j] - 0.01f * m;
        }
    }
}

__global__ void zero_k(float* __restrict__ p, long n)
{
    long i = (long)blockIdx.x * 256 + threadIdx.x;
    const long st = (long)gridDim.x * 256;
    for (; i < n; i += st) p[i] = 0.f;
}

extern "C" void kernel_launch(void* const* d_in, const int* in_sizes, int n_in,
                              void* d_out, int out_size, void* d_ws, size_t ws_size,
                              hipStream_t stream)
{
    const float* x          = (const float*)d_in[0];
    const float* wq_ctx     = (const float*)d_in[1];
    const float* wq         = (const float*)d_in[2];
    const float* wk         = (const float*)d_in[3];
    const float* wv         = (const float*)d_in[4];
    const float* w_attn_out = (const float*)d_in[5];
    const float* w_gate     = (const float*)d_in[6];
    const float* gate_g     = (const float*)d_in[7];
    const float* gate_b     = (const float*)d_in[8];
    const float* n1_g       = (const float*)d_in[9];
    const float* n1_b       = (const float*)d_in[10];
    const float* n2_g       = (const float*)d_in[11];
    const float* n2_b       = (const float*)d_in[12];
    const float* ffn_w1     = (const float*)d_in[13];
    const float* ffn_b1     = (const float*)d_in[14];
    const float* ffn_w2     = (const float*)d_in[15];
    const float* ffn_b2     = (const float*)d_in[16];
    const float* pers       = (const float*)d_in[17];
    const float* mem_w0_in  = (const float*)d_in[18];
    const float* mem_b0_in  = (const float*)d_in[19];
    const float* mem_w1_in  = (const float*)d_in[20];
    const float* mem_b1_in  = (const float*)d_in[21];
    const float* mem_wk     = (const float*)d_in[22];
    const float* mem_wv     = (const float*)d_in[23];
    float* out = (float*)d_out;
    (void)in_sizes; (void)n_in; (void)out_size; (void)ws_size;

    char* cur = (char*)d_ws;
    auto allocF = [&](size_t n) { float* p = (float*)cur; cur += n * 4; return p; };
    auto allocH = [&](size_t n) { _Float16* p = (_Float16*)cur; cur += n * 2; return p; };

    float* mw0   = allocF((size_t)DD * HH);
    float* mw1   = allocF((size_t)HH * DD);
    float* mb0   = allocF(HH);
    float* mb1   = allocF(DD);
    float* mom   = allocF((size_t)DD * HH * 2 + HH + DD);
    float* mom_w0 = mom, *mom_w1 = mom + (size_t)DD * HH;
    float* mom_b0 = mom_w1 + (size_t)HH * DD, *mom_b1 = mom_b0 + HH;
    float* F32A  = allocF((size_t)1024 * DD);
    float* F32B  = allocF((size_t)1024 * DD);
    float* F32C  = allocF((size_t)1024 * HH);
    float* F32QK = allocF((size_t)2112 * 2048);
    float* YTF   = allocF((size_t)1024 * DD);
    float* OF    = allocF((size_t)1024 * DD);
    float* db0   = allocF(HH);
    float* db1   = allocF(DD);

    _Float16* x16    = allocH((size_t)2 * TT * DD);
    _Float16* wqcT   = allocH((size_t)DD * DD);
    _Float16* wqkT   = allocH((size_t)2048 * DD);
    _Float16* wvT    = allocH((size_t)DD * DD);
    _Float16* waoT   = allocH((size_t)DD * DD);
    _Float16* wgT    = allocH((size_t)DD * DD);
    _Float16* wmixT  = allocH((size_t)3072 * DD);
    _Float16* f1T    = allocH((size_t)FFd * DD);
    _Float16* f2T    = allocH((size_t)DD * FFd);
    _Float16* w0T    = allocH((size_t)HH * DD);
    _Float16* w1T    = allocH((size_t)DD * HH);
    _Float16* w1p    = allocH((size_t)HH * DD);
    _Float16* xn16   = allocH((size_t)1024 * DD);
    _Float16* h116   = allocH((size_t)1024 * HH);
    _Float16* laug16 = allocH((size_t)2208 * DD);
    _Float16* q16    = allocH((size_t)1024 * DD);
    _Float16* k16    = allocH((size_t)2208 * DD);
    _Float16* vT16   = allocH((size_t)2 * DD * KA);
    _Float16* pr16   = allocH((size_t)2 * 512 * KA);
    _Float16* ao16   = allocH((size_t)1024 * DD);
    _Float16* yt16   = allocH((size_t)1024 * DD);
    _Float16* kk16   = allocH((size_t)1024 * DD);
    _Float16* kkT16  = allocH((size_t)DD * 1024);
    _Float16* hs16   = allocH((size_t)1024 * HH);
    _Float16* hsT16  = allocH((size_t)HH * 1024);
    _Float16* r16    = allocH((size_t)1024 * DD);
    _Float16* rT16   = allocH((size_t)DD * 1024);
    _Float16* da0T   = allocH((size_t)HH * 1024);
    _Float16* qm16   = allocH((size_t)1024 * DD);
    _Float16* a216   = allocH((size_t)1024 * HH);
    _Float16* gl16   = allocH((size_t)1024 * DD);
    _Float16* h216   = allocH((size_t)1024 * DD);
    _Float16* f116   = allocH((size_t)1024 * FFd);

    auto launch = [&](int bm, int nz, const GP& g) {
        dim3 grid((g.N + 127) / 128, (g.M + bm - 1) / bm, nz);
        if (bm == 128) gemm16<128><<<grid, 256, 0, stream>>>(g);
        else           gemm16<64><<<grid, 256, 0, stream>>>(g);
    };

    // ---- init ----
    hipMemcpyAsync(mw0, mem_w0_in, sizeof(float) * DD * HH, hipMemcpyDeviceToDevice, stream);
    hipMemcpyAsync(mw1, mem_w1_in, sizeof(float) * HH * DD, hipMemcpyDeviceToDevice, stream);
    hipMemcpyAsync(mb0, mem_b0_in, sizeof(float) * HH, hipMemcpyDeviceToDevice, stream);
    hipMemcpyAsync(mb1, mem_b1_in, sizeof(float) * DD, hipMemcpyDeviceToDevice, stream);
    zero_k<<<4096, 256, 0, stream>>>(mom, (long)DD * HH * 2 + HH + DD);
    cvt_k<<<(2 * TT * DD) / 1024, 256, 0, stream>>>(x, x16, (long)2 * TT * DD);
    auto T64 = [&](const float* in, _Float16* o, int R, int C) {
        cvtT_k<<<dim3(C / 64, R / 64), 256, 0, stream>>>(in, o, R, C);
    };
    T64(wq_ctx, wqcT, DD, DD);
    T64(wq, wqkT, DD, DD); T64(wk, wqkT + (size_t)1024 * DD, DD, DD);
    T64(wv, wvT, DD, DD); T64(w_attn_out, waoT, DD, DD); T64(w_gate, wgT, DD, DD);
    T64(mem_wk, wmixT, DD, DD); T64(mem_wv, wmixT + (size_t)1024 * DD, DD, DD);
    T64(wq_ctx, wmixT + (size_t)2048 * DD, DD, DD);
    T64(ffn_w1, f1T, DD, FFd); T64(ffn_w2, f2T, FFd, DD);
    T64(mem_w0_in, w0T, DD, HH); T64(mem_w1_in, w1T, HH, DD);
    cvt_k<<<(HH * DD) / 1024, 256, 0, stream>>>(mem_w1_in, w1p, (long)HH * DD);

    for (int c = 0; c < NCH; ++c) {
        GP g;
        // 1. xn_pre = seg @ wq_ctx  (z=2)
        g = GP{}; g.A = x16 + (long)c * CC * DD; g.bsA = (long)TT * DD; g.Bt = wqcT;
        g.Cf = F32A; g.ldc = DD; g.bsC = (long)CC * DD;
        g.s1 = 1.f; g.M = CC; g.N = DD; g.K = DD;
        launch(64, 2, g);
        l2n16s_k<<<1024, 256, 0, stream>>>(F32A, DD, xn16, 1.f);
        // 2. h = mem_mlp(mem, xn)
        g = GP{}; g.A = xn16; g.Bt = w0T; g.bias = mb0; g.Ch = h116; g.ldh = HH;
        g.s1 = 1.f; g.M = 1024; g.N = HH; g.K = DD; g.act = 1;
        launch(64, 1, g);
        g = GP{}; g.A = h116; g.Bt = w1T; g.bias = mb1; g.Cf = F32B; g.ldc = DD;
        g.s1 = 1.f; g.M = 1024; g.N = DD; g.K = HH;
        launch(64, 1, g);
        lnaug_k<<<2 * SB, 256, 0, stream>>>(x, pers, F32B, n1_g, n1_b, laug16, c);
        // 3. q|k fused
        g = GP{}; g.A = laug16; g.Bt = wqkT; g.Cf = F32QK; g.ldc = 2048;
        g.s1 = 1.f; g.M = 2 * SB; g.N = 2048; g.K = DD;
        launch(64, 1, g);
        l2nq_k<<<1024, 256, 0, stream>>>(F32QK, q16);
        l2n16s_k<<<2 * SB, 256, 0, stream>>>(F32QK + 1024, 2048, k16, 1.f);
        // 4. v (transposed out)
        g = GP{}; g.A = laug16; g.bsA = (long)SB * DD; g.Bt = wvT;
        g.Ct = vT16; g.ldt = KA; g.bsT = (long)DD * KA;
        g.s1 = 1.f; g.M = SB; g.N = DD; g.K = DD;
        launch(64, 2, g);
        // 5. scores + softmax + PV
        g = GP{}; g.A = q16; g.bsA = (long)512 * DD; g.Bt = k16; g.bsB = (long)SB * DD;
        g.Cf = F32C; g.ldc = SB; g.bsC = (long)512 * SB;
        g.s1 = 1.f; g.M = 512; g.N = SB; g.K = DD;
        launch(64, 2, g);
        softmax16_k<<<1024, 256, 0, stream>>>(F32C, pr16);
        g = GP{}; g.A = pr16; g.bsA = (long)512 * KA; g.Bt = vT16; g.bsB = (long)DD * KA;
        g.Ch = ao16; g.ldh = DD; g.bsH = (long)512 * DD;
        g.s1 = 1.f; g.M = 512; g.N = DD; g.K = KA;
        launch(64, 2, g);
        // 6. y_t = seg + attn @ wao
        g = GP{}; g.A = ao16; g.bsA = (long)512 * DD; g.Bt = waoT;
        g.resid = x + (long)c * CC * DD; g.ldr = DD; g.bsR = (long)TT * DD;
        g.Cf = YTF; g.ldc = DD; g.bsC = (long)512 * DD;
        g.Ch = yt16; g.ldh = DD; g.bsH = (long)512 * DD;
        g.s1 = 1.f; g.s2 = 1.f; g.M = 512; g.N = DD; g.K = DD;
        launch(64, 2, g);
        // 7. kk | vv | qm_pre fused (act 4)
        g = GP{}; g.A = yt16; g.Bt = wmixT; g.Ch = kk16; g.Ct = kkT16;
        g.Cf = F32B; g.Cf2 = F32A;
        g.s1 = 1.f; g.M = 1024; g.N = 3072; g.K = DD; g.act = 4;
        launch(64, 1, g);
        // 8. a0 = kk@w0+b0 (raw) ; hs/hsT = silu
        g = GP{}; g.A = kk16; g.Bt = w0T; g.bias = mb0; g.Cf = F32C; g.ldc = HH;
        g.Ch = hs16; g.ldh = HH; g.Ct = hsT16; g.ldt = 1024;
        g.s1 = 1.f; g.M = 1024; g.N = HH; g.K = DD; g.act = 1;
        launch(64, 1, g);
        // 9. r = (hs@w1 + b1 - vv)/1024
        g = GP{}; g.A = hs16; g.Bt = w1T; g.bias = mb1;
        g.resid = F32B; g.ldr = DD;
        g.Ch = r16; g.ldh = DD; g.Ct = rT16; g.ldt = 1024;
        g.s1 = 1.f / 1024.f; g.s2 = -1.f / 1024.f; g.M = 1024; g.N = DD; g.K = HH;
        launch(64, 1, g);
        rowsum16_k<<<1024, 256, 0, stream>>>(rT16, db1);
        // 10. da0T = (r @ w1_old^T) * dsilu(a0)   (before w1 update!)
        g = GP{}; g.A = r16; g.Bt = w1p; g.aux = F32C; g.ldx = HH;
        g.Ct = da0T; g.ldt = 1024;
        g.s1 = 1.f; g.M = 1024; g.N = HH; g.K = DD; g.act = 2;
        launch(64, 1, g);
        rowsum16_k<<<HH, 256, 0, stream>>>(da0T, db0);
        // 11. dW1 + momentum + update (act 3): M=H, N=D
        g = GP{}; g.A = hsT16; g.Bt = rT16; g.Cf = mw1; g.ldc = DD; g.Mom = mom_w1;
        g.Ch = w1p; g.ldh = DD; g.Ct = w1T; g.ldt = HH;
        g.M = HH; g.N = DD; g.K = 1024; g.act = 3;
        launch(64, 1, g);
        // 12. dW0 + momentum + update: M=D, N=H
        g = GP{}; g.A = kkT16; g.Bt = da0T; g.Cf = mw0; g.ldc = HH; g.Mom = mom_w0;
        g.Ct = w0T; g.ldt = DD;
        g.M = DD; g.N = HH; g.K = 1024; g.act = 3;
        launch(64, 1, g);
        biasup_k<<<12, 256, 0, stream>>>(mb0, mom_b0, db0, mb1, mom_b1, db1);
        // 13. mem_out = mem_mlp(new mem, l2norm(qm_pre))
        l2n16s_k<<<1024, 256, 0, stream>>>(F32A, DD, qm16, 1.f);
        g = GP{}; g.A = qm16; g.Bt = w0T; g.bias = mb0; g.Ch = a216; g.ldh = HH;
        g.s1 = 1.f; g.M = 1024; g.N = HH; g.K = DD; g.act = 1;
        launch(64, 1, g);
        g = GP{}; g.A = a216; g.Bt = w1T; g.bias = mb1; g.Cf = F32B; g.ldc = DD;
        g.s1 = 1.f; g.M = 1024; g.N = DD; g.K = HH;
        launch(64, 1, g);
        // 14. gate
        ln16_k<<<1024, 256, 0, stream>>>(YTF, gate_g, gate_b, gl16);
        g = GP{}; g.A = gl16; g.Bt = wgT; g.Cf = F32C; g.ldc = DD;
        g.s1 = 1.f; g.M = 1024; g.N = DD; g.K = DD;
        launch(64, 1, g);
        gateln2_k<<<1024, 256, 0, stream>>>(YTF, F32C, F32B, n2_g, n2_b, OF, h216);
        // 15. FFN
        g = GP{}; g.A = h216; g.Bt = f1T; g.bias = ffn_b1; g.Ch = f116; g.ldh = FFd;
        g.s1 = 1.f; g.M = 1024; g.N = FFd; g.K = DD; g.act = 1;
        launch(128, 1, g);
        g = GP{}; g.A = f116; g.bsA = (long)512 * FFd; g.Bt = f2T; g.bias = ffn_b2;
        g.resid = OF; g.ldr = DD; g.bsR = (long)512 * DD;
        g.Cf = out + (long)c * CC * DD; g.ldc = DD; g.bsC = (long)TT * DD;
        g.s1 = 1.f; g.s2 = 1.f; g.M = 512; g.N = DD; g.K = FFd;
        launch(64, 2, g);
    }
}

// Round 4
// 4494.456 us; speedup vs baseline: 3.7414x; 1.2706x over previous
//
#include <hip/hip_runtime.h>

#define DD 1024
#define HH 2048
#define TT 4096
#define CC 512
#define PPc 16
#define SB 1040   // per-batch aug rows
#define KA 1088   // padded attention K (multiple of 64)
#define FFd 4096
#define NCH 8

typedef _Float16 f16x8 __attribute__((ext_vector_type(8)));
typedef float f32x4 __attribute__((ext_vector_type(4)));

typedef const __attribute__((address_space(1))) _Float16* gas_t;
typedef __attribute__((address_space(3))) _Float16* las_t;

__device__ __forceinline__ void async_cp16(const _Float16* g, _Float16* l) {
    __builtin_amdgcn_global_load_lds((gas_t)g, (las_t)l, 16, 0, 0);
}

struct GP {
    const _Float16* A; long bsA;
    const _Float16* Bt; long bsB;
    const float* bias;
    const float* resid; long ldr, bsR;
    const float* aux;   long ldx, bsX;
    float* Cf; long ldc, bsC;
    _Float16* Ch; long ldh, bsH;
    _Float16* Ct; long ldt, bsT;
    float* Mom;
    float* Cf2;
    float s1, s2;
    int M, N, K, act;
};

// acts: 0 plain, 1 silu (Cf<-raw, Ch/Ct<-silu*s1+resid), 2 mul-by-dsilu(aux),
//       3 momentum weight update (Cf=master w, Mom=momentum, Ch/Ct new f16 w),
//       4 routing (n<1024 -> Ch(+Ct), <2048 -> Cf, else Cf2; all ld 1024)
// K % 64 == 0. Ct GEMMs require M % 8 == 0.
template<int BM>
__global__ __launch_bounds__(256) void gemm16(GP g)
{
    constexpr int BN = 128;
    constexpr int WM = BM / 2, WN = 64;
    constexpr int FA = WM / 16, FB = 4;
    constexpr int ASZ = 2 * 2 * BM * 32;   // dbuf x 2 k-panels
    constexpr int BSZ = 2 * 2 * BN * 32;
    __shared__ _Float16 smem[ASZ + BSZ];
    const int tid = threadIdx.x;
    const int z = blockIdx.z;
    const int K = g.K;
    const _Float16* Ab = g.A + (long)z * g.bsA;
    const _Float16* Bb = g.Bt + (long)z * g.bsB;
    const int m0 = blockIdx.y * BM, n0 = blockIdx.x * BN;
    const int wave = tid >> 6, lane = tid & 63;
    const int wr = wave >> 1, wc = wave & 1;
    const int fr = lane & 15, kq = lane >> 4;
    f32x4 acc[FA][FB] = {};
    const int srow = tid >> 2;             // 0..63
    const int scol = (tid & 3) * 8;        // f16 units within 32-k panel

    auto stage = [&](int p, int kk) {
#pragma unroll
        for (int h = 0; h < 2; ++h) {
#pragma unroll
            for (int r = 0; r < BM / 64; ++r)
                async_cp16(Ab + (long)(m0 + r * 64 + srow) * K + kk + h * 32 + scol,
                           &smem[p * 2 * BM * 32 + h * BM * 32 + r * 2048 + wave * 512]);
#pragma unroll
            for (int r = 0; r < 2; ++r)
                async_cp16(Bb + (long)(n0 + r * 64 + srow) * K + kk + h * 32 + scol,
                           &smem[ASZ + p * 2 * BN * 32 + h * BN * 32 + r * 2048 + wave * 512]);
        }
    };

    stage(0, 0);
    int p = 0;
    for (int k0 = 0; k0 < K; k0 += 64) {
        __syncthreads();
        if (k0 + 64 < K) stage(p ^ 1, k0 + 64);
        f16x8 af[2][FA], bf[2][FB];
#pragma unroll
        for (int h = 0; h < 2; ++h) {
#pragma unroll
            for (int i = 0; i < FA; ++i)
                af[h][i] = *(const f16x8*)&smem[p * 2 * BM * 32 + h * BM * 32 +
                                               (wr * WM + i * 16 + fr) * 32 + kq * 8];
#pragma unroll
            for (int j = 0; j < FB; ++j)
                bf[h][j] = *(const f16x8*)&smem[ASZ + p * 2 * BN * 32 + h * BN * 32 +
                                               (wc * WN + j * 16 + fr) * 32 + kq * 8];
        }
#pragma unroll
        for (int h = 0; h < 2; ++h)
#pragma unroll
            for (int i = 0; i < FA; ++i)
#pragma unroll
                for (int j = 0; j < FB; ++j)
                    acc[i][j] = __builtin_amdgcn_mfma_f32_16x16x32_f16(af[h][i], bf[h][j], acc[i][j], 0, 0, 0);
        p ^= 1;
    }

    // ---- finalize values in acc ----
#pragma unroll
    for (int i = 0; i < FA; ++i) {
        const int gm0 = m0 + wr * WM + i * 16 + kq * 4;
#pragma unroll
        for (int j = 0; j < FB; ++j) {
            const int gn = n0 + wc * WN + j * 16 + fr;
            if (gn >= g.N) continue;
            if (g.act == 3) {
#pragma unroll
                for (int r = 0; r < 4; ++r) {
                    const int gm = gm0 + r;
                    if (gm >= g.M) continue;
                    const long idx = (long)gm * g.ldc + gn;
                    const float m = 0.9f * g.Mom[idx] + acc[i][j][r];
                    g.Mom[idx] = m;
                    const float v = 0.99f * g.Cf[idx] - 0.01f * m;
                    g.Cf[idx] = v;
                    if (g.Ch) g.Ch[(long)gm * g.ldh + gn] = (_Float16)v;
                    acc[i][j][r] = v;
                }
            } else if (g.act == 4) {
                const int seg = gn >> 10, gl = gn & 1023;
#pragma unroll
                for (int r = 0; r < 4; ++r) {
                    const int gm = gm0 + r;
                    if (gm >= g.M) continue;
                    const float v = acc[i][j][r];
                    if (seg == 0) g.Ch[(long)gm * 1024 + gl] = (_Float16)v;
                    else if (seg == 1) g.Cf[(long)gm * 1024 + gl] = v;
                    else g.Cf2[(long)gm * 1024 + gl] = v;
                }
            } else {
                const float bv = g.bias ? g.bias[gn] : 0.f;
#pragma unroll
                for (int r = 0; r < 4; ++r) {
                    const int gm = gm0 + r;
                    if (gm >= g.M) continue;
                    const float raw = acc[i][j][r] + bv;
                    float av = raw;
                    if (g.act == 1) av = raw / (1.f + __expf(-raw));
                    else if (g.act == 2) {
                        const float a = g.aux[(long)z * g.bsX + (long)gm * g.ldx + gn];
                        const float s = 1.f / (1.f + __expf(-a));
                        av = raw * (s * (1.f + a * (1.f - s)));
                    }
                    float v = g.s1 * av;
                    if (g.resid) v += g.s2 * g.resid[(long)z * g.bsR + (long)gm * g.ldr + gn];
                    if (g.Cf) g.Cf[(long)z * g.bsC + (long)gm * g.ldc + gn] = (g.act == 1) ? raw : v;
                    if (g.Ch) g.Ch[(long)z * g.bsH + (long)gm * g.ldh + gn] = (_Float16)v;
                    acc[i][j][r] = v;
                }
            }
        }
    }

    // ---- coalesced transposed store via LDS ----
    if (g.Ct && (g.act != 4 || n0 < 1024)) {
        constexpr int TP = BM + 8;
        __syncthreads();
#pragma unroll
        for (int i = 0; i < FA; ++i) {
            const int lm = wr * WM + i * 16 + kq * 4;
#pragma unroll
            for (int j = 0; j < FB; ++j) {
                const int ln = wc * WN + j * 16 + fr;
#pragma unroll
                for (int r = 0; r < 4; ++r)
                    smem[ln * TP + lm + r] = (_Float16)acc[i][j][r];
            }
        }
        __syncthreads();
        const int ln = tid >> 1, half = tid & 1;
        const int gn = n0 + ln;
        if (gn < g.N) {
            const int gmb = m0 + half * (BM / 2);
            _Float16* dst = g.Ct + (long)z * g.bsT + (long)gn * g.ldt + gmb;
            const _Float16* src = &smem[ln * TP + half * (BM / 2)];
#pragma unroll
            for (int gi = 0; gi < BM / 16; ++gi)
                if (gmb + gi * 8 < g.M)
                    *(uint4*)(dst + gi * 8) = *(const uint4*)(src + gi * 8);
        }
    }
}

// ---- elementwise / rowwise ----
__global__ void cvt_k(const float* __restrict__ in, _Float16* __restrict__ out, long n)
{
    long i = ((long)blockIdx.x * 256 + threadIdx.x) * 4;
    if (i >= n) return;
    const float4 v = *(const float4*)(in + i);
    out[i] = (_Float16)v.x; out[i + 1] = (_Float16)v.y;
    out[i + 2] = (_Float16)v.z; out[i + 3] = (_Float16)v.w;
}

__global__ void cvtT_k(const float* __restrict__ in, _Float16* __restrict__ out, int R, int C)
{
    __shared__ _Float16 t[64][65];
    const int c0 = blockIdx.x * 64, r0 = blockIdx.y * 64;
    const int tid = threadIdx.x;
    for (int i = 0; i < 16; ++i) {
        const int lin = i * 256 + tid;
        const int r = lin >> 6, cc = lin & 63;
        t[r][cc] = (_Float16)in[(long)(r0 + r) * C + c0 + cc];
    }
    __syncthreads();
    for (int i = 0; i < 16; ++i) {
        const int lin = i * 256 + tid;
        const int r2 = lin >> 6, c2 = lin & 63;
        out[(long)(c0 + r2) * R + r0 + c2] = t[c2][r2];
    }
}

__global__ void l2n16s_k(const float* __restrict__ in, long ld,
                         _Float16* __restrict__ out, float scale)
{
    const long row = blockIdx.x;
    const float* p = in + row * ld;
    _Float16* q = out + row * DD;
    const int t = threadIdx.x;
    float e0 = p[t], e1 = p[t + 256], e2 = p[t + 512], e3 = p[t + 768];
    __shared__ float rq[256];
    rq[t] = e0 * e0 + e1 * e1 + e2 * e2 + e3 * e3;
    __syncthreads();
    for (int k = 128; k; k >>= 1) { if (t < k) rq[t] += rq[t + k]; __syncthreads(); }
    const float f = scale / fmaxf(sqrtf(rq[0]), 1e-12f);
    q[t] = (_Float16)(e0 * f); q[t + 256] = (_Float16)(e1 * f);
    q[t + 512] = (_Float16)(e2 * f); q[t + 768] = (_Float16)(e3 * f);
}

// fused q + k l2norm from F32QK [2080][2048]
__global__ void l2qk_k(const float* __restrict__ qk, _Float16* __restrict__ q16,
                       _Float16* __restrict__ k16)
{
    const int blk = blockIdx.x;     // 0..3103
    const float* p; _Float16* o; float scale;
    if (blk < 1024) {
        const int b = blk >> 9, r = blk & 511;
        p = qk + (long)(b * SB + PPc + CC + r) * 2048;
        o = q16 + (long)blk * DD; scale = 32.f;
    } else {
        const int row = blk - 1024;
        p = qk + (long)row * 2048 + 1024;
        o = k16 + (long)row * DD; scale = 1.f;
    }
    const int t = threadIdx.x;
    float e0 = p[t], e1 = p[t + 256], e2 = p[t + 512], e3 = p[t + 768];
    __shared__ float rq[256];
    rq[t] = e0 * e0 + e1 * e1 + e2 * e2 + e3 * e3;
    __syncthreads();
    for (int k = 128; k; k >>= 1) { if (t < k) rq[t] += rq[t + k]; __syncthreads(); }
    const float f = scale / fmaxf(sqrtf(rq[0]), 1e-12f);
    o[t] = (_Float16)(e0 * f); o[t + 256] = (_Float16)(e1 * f);
    o[t + 512] = (_Float16)(e2 * f); o[t + 768] = (_Float16)(e3 * f);
}

__global__ void ln16_k(const float* __restrict__ x, const float* __restrict__ g,
                       const float* __restrict__ b, _Float16* __restrict__ o)
{
    const long row = blockIdx.x;
    const float* p = x + row * DD;
    _Float16* q = o + row * DD;
    const int t = threadIdx.x;
    float e0 = p[t], e1 = p[t + 256], e2 = p[t + 512], e3 = p[t + 768];
    __shared__ float rs[256], rq[256];
    rs[t] = e0 + e1 + e2 + e3;
    rq[t] = e0 * e0 + e1 * e1 + e2 * e2 + e3 * e3;
    __syncthreads();
    for (int k = 128; k; k >>= 1) {
        if (t < k) { rs[t] += rs[t + k]; rq[t] += rq[t + k]; }
        __syncthreads();
    }
    const float mean = rs[0] * (1.f / DD);
    const float inv = rsqrtf(rq[0] * (1.f / DD) - mean * mean + 1e-5f);
    q[t]       = (_Float16)((e0 - mean) * inv * g[t]       + b[t]);
    q[t + 256] = (_Float16)((e1 - mean) * inv * g[t + 256] + b[t + 256]);
    q[t + 512] = (_Float16)((e2 - mean) * inv * g[t + 512] + b[t + 512]);
    q[t + 768] = (_Float16)((e3 - mean) * inv * g[t + 768] + b[t + 768]);
}

__global__ void lnaug_k(const float* __restrict__ x, const float* __restrict__ pers,
                        const float* __restrict__ h, const float* __restrict__ g,
                        const float* __restrict__ b, _Float16* __restrict__ out, int c)
{
    const int row = blockIdx.x;             // 0..2079
    const int bb = row / SB, i = row % SB;
    const float* p;
    if (i < PPc) p = pers + (long)i * DD;
    else if (i < PPc + CC) p = h + (long)(bb * CC + i - PPc) * DD;
    else p = x + (long)(bb * TT + c * CC + (i - PPc - CC)) * DD;
    _Float16* q = out + (long)row * DD;
    const int t = threadIdx.x;
    float e0 = p[t], e1 = p[t + 256], e2 = p[t + 512], e3 = p[t + 768];
    __shared__ float rs[256], rq[256];
    rs[t] = e0 + e1 + e2 + e3;
    rq[t] = e0 * e0 + e1 * e1 + e2 * e2 + e3 * e3;
    __syncthreads();
    for (int k = 128; k; k >>= 1) {
        if (t < k) { rs[t] += rs[t + k]; rq[t] += rq[t + k]; }
        __syncthreads();
    }
    const float mean = rs[0] * (1.f / DD);
    const float inv = rsqrtf(rq[0] * (1.f / DD) - mean * mean + 1e-5f);
    q[t]       = (_Float16)((e0 - mean) * inv * g[t]       + b[t]);
    q[t + 256] = (_Float16)((e1 - mean) * inv * g[t + 256] + b[t + 256]);
    q[t + 512] = (_Float16)((e2 - mean) * inv * g[t + 512] + b[t + 512]);
    q[t + 768] = (_Float16)((e3 - mean) * inv * g[t + 768] + b[t + 768]);
}

__global__ void softmax16_k(const float* __restrict__ sc, _Float16* __restrict__ pr)
{
    const int blk = blockIdx.x;             // 0..1023
    const int r = blk & 511;
    const int i = PPc + CC + r;
    const float* p = sc + (long)blk * SB;
    _Float16* q = pr + (long)blk * KA;
    const int t = threadIdx.x;
    __shared__ float red[256];
    float mx = -3.0e38f;
    for (int j = t; j < SB; j += 256)
        if (j <= i) mx = fmaxf(mx, p[j]);
    red[t] = mx; __syncthreads();
    for (int k = 128; k; k >>= 1) { if (t < k) red[t] = fmaxf(red[t], red[t + k]); __syncthreads(); }
    mx = red[0]; __syncthreads();
    float sum = 0.f;
    for (int j = t; j < SB; j += 256)
        if (j <= i) sum += __expf(p[j] - mx);
    red[t] = sum; __syncthreads();
    for (int k = 128; k; k >>= 1) { if (t < k) red[t] += red[t + k]; __syncthreads(); }
    const float inv = 1.f / red[0];
    for (int j = t; j < KA; j += 256) {
        float e = 0.f;
        if (j < SB && j <= i) e = __expf(p[j] - mx) * inv;
        q[j] = (_Float16)e;
    }
}

__global__ void gateln2_k(const float* __restrict__ yt, const float* __restrict__ gp,
                          const float* __restrict__ mo, const float* __restrict__ g,
                          const float* __restrict__ b, float* __restrict__ OF,
                          _Float16* __restrict__ o16)
{
    const long row = blockIdx.x;
    const int t = threadIdx.x;
    float e[4];
    __shared__ float rs[256], rq[256];
    float ssum = 0.f, qsum = 0.f;
#pragma unroll
    for (int k = 0; k < 4; ++k) {
        const long idx = row * DD + t + k * 256;
        const float s = 1.f / (1.f + __expf(-gp[idx]));
        e[k] = yt[idx] * s + mo[idx] * (1.f - s);
        OF[idx] = e[k];
        ssum += e[k]; qsum += e[k] * e[k];
    }
    rs[t] = ssum; rq[t] = qsum;
    __syncthreads();
    for (int k = 128; k; k >>= 1) {
        if (t < k) { rs[t] += rs[t + k]; rq[t] += rq[t + k]; }
        __syncthreads();
    }
    const float mean = rs[0] * (1.f / DD);
    const float inv = rsqrtf(rq[0] * (1.f / DD) - mean * mean + 1e-5f);
#pragma unroll
    for (int k = 0; k < 4; ++k) {
        const int cc = t + k * 256;
        o16[row * DD + cc] = (_Float16)((e[k] - mean) * inv * g[cc] + b[cc]);
    }
}

// db1 = rowsum(rT16 [1024][1024]), db0 = rowsum(da0T [2048][1024])
__global__ void rowsum2_k(const _Float16* __restrict__ rT, const _Float16* __restrict__ daT,
                          float* __restrict__ db1, float* __restrict__ db0)
{
    const int blk = blockIdx.x;   // 0..3071
    const _Float16* p; float* o;
    if (blk < 1024) { p = rT + (long)blk * 1024; o = db1 + blk; }
    else { p = daT + (long)(blk - 1024) * 1024; o = db0 + (blk - 1024); }
    const int t = threadIdx.x;
    __shared__ float red[256];
    red[t] = (float)p[t] + (float)p[t + 256] + (float)p[t + 512] + (float)p[t + 768];
    __syncthreads();
    for (int k = 128; k; k >>= 1) { if (t < k) red[t] += red[t + k]; __syncthreads(); }
    if (t == 0) *o = red[0];
}

__global__ void biasup_k(float* __restrict__ mb0, float* __restrict__ mob0,
                         const float* __restrict__ db0,
                         float* __restrict__ mb1, float* __restrict__ mob1,
                         const float* __restrict__ db1)
{
    const int i = blockIdx.x * 256 + threadIdx.x;
    if (i < HH) {
        const float m = 0.9f * mob0[i] + db0[i];
        mob0[i] = m;
        mb0[i] = 0.99f * mb0[i] - 0.01f * m;
    } else {
        const int j = i - HH;
        if (j < DD) {
            const float m = 0.9f * mob1[j] + db1[j];
            mob1[j] = m;
            mb1[j] = 0.99f * mb1[j] - 0.01f * m;
        }
    }
}

__global__ void zero_k(float* __restrict__ p, long n)
{
    long i = (long)blockIdx.x * 256 + threadIdx.x;
    const long st = (long)gridDim.x * 256;
    for (; i < n; i += st) p[i] = 0.f;
}

extern "C" void kernel_launch(void* const* d_in, const int* in_sizes, int n_in,
                              void* d_out, int out_size, void* d_ws, size_t ws_size,
                              hipStream_t stream)
{
    const float* x          = (const float*)d_in[0];
    const float* wq_ctx     = (const float*)d_in[1];
    const float* wq         = (const float*)d_in[2];
    const float* wk         = (const float*)d_in[3];
    const float* wv         = (const float*)d_in[4];
    const float* w_attn_out = (const float*)d_in[5];
    const float* w_gate     = (const float*)d_in[6];
    const float* gate_g     = (const float*)d_in[7];
    const float* gate_b     = (const float*)d_in[8];
    const float* n1_g       = (const float*)d_in[9];
    const float* n1_b       = (const float*)d_in[10];
    const float* n2_g       = (const float*)d_in[11];
    const float* n2_b       = (const float*)d_in[12];
    const float* ffn_w1     = (const float*)d_in[13];
    const float* ffn_b1     = (const float*)d_in[14];
    const float* ffn_w2     = (const float*)d_in[15];
    const float* ffn_b2     = (const float*)d_in[16];
    const float* pers       = (const float*)d_in[17];
    const float* mem_w0_in  = (const float*)d_in[18];
    const float* mem_b0_in  = (const float*)d_in[19];
    const float* mem_w1_in  = (const float*)d_in[20];
    const float* mem_b1_in  = (const float*)d_in[21];
    const float* mem_wk     = (const float*)d_in[22];
    const float* mem_wv     = (const float*)d_in[23];
    float* out = (float*)d_out;
    (void)in_sizes; (void)n_in; (void)out_size; (void)ws_size;

    char* cur = (char*)d_ws;
    auto allocF = [&](size_t n) { float* p = (float*)cur; cur += n * 4; return p; };
    auto allocH = [&](size_t n) { _Float16* p = (_Float16*)cur; cur += n * 2; return p; };

    float* mw0   = allocF((size_t)DD * HH);
    float* mw1   = allocF((size_t)HH * DD);
    float* mb0   = allocF(HH);
    float* mb1   = allocF(DD);
    float* mom   = allocF((size_t)DD * HH * 2 + HH + DD);
    float* mom_w0 = mom, *mom_w1 = mom + (size_t)DD * HH;
    float* mom_b0 = mom_w1 + (size_t)HH * DD, *mom_b1 = mom_b0 + HH;
    float* F32A  = allocF((size_t)1024 * DD);
    float* F32B  = allocF((size_t)1024 * DD);
    float* F32C  = allocF((size_t)1024 * HH);
    float* F32QK = allocF((size_t)2112 * 2048);
    float* YTF   = allocF((size_t)1024 * DD);
    float* OF    = allocF((size_t)1024 * DD);
    float* db0   = allocF(HH);
    float* db1   = allocF(DD);

    _Float16* x16    = allocH((size_t)2 * TT * DD);
    _Float16* wqcT   = allocH((size_t)DD * DD);
    _Float16* wqkT   = allocH((size_t)2048 * DD);
    _Float16* wvT    = allocH((size_t)DD * DD);
    _Float16* waoT   = allocH((size_t)DD * DD);
    _Float16* wgT    = allocH((size_t)DD * DD);
    _Float16* wmixT  = allocH((size_t)3072 * DD);
    _Float16* f1T    = allocH((size_t)FFd * DD);
    _Float16* f2T    = allocH((size_t)DD * FFd);
    _Float16* w0T    = allocH((size_t)HH * DD);
    _Float16* w1T    = allocH((size_t)DD * HH);
    _Float16* w1p    = allocH((size_t)HH * DD);
    _Float16* xn16   = allocH((size_t)1024 * DD);
    _Float16* h116   = allocH((size_t)1024 * HH);
    _Float16* laug16 = allocH((size_t)2208 * DD);
    _Float16* q16    = allocH((size_t)1024 * DD);
    _Float16* k16    = allocH((size_t)2208 * DD);
    _Float16* vT16   = allocH((size_t)2 * DD * KA);
    _Float16* pr16   = allocH((size_t)2 * 512 * KA);
    _Float16* ao16   = allocH((size_t)1024 * DD);
    _Float16* yt16   = allocH((size_t)1024 * DD);
    _Float16* kk16   = allocH((size_t)1024 * DD);
    _Float16* kkT16  = allocH((size_t)DD * 1024);
    _Float16* hs16   = allocH((size_t)1024 * HH);
    _Float16* hsT16  = allocH((size_t)HH * 1024);
    _Float16* r16    = allocH((size_t)1024 * DD);
    _Float16* rT16   = allocH((size_t)DD * 1024);
    _Float16* da0T   = allocH((size_t)HH * 1024);
    _Float16* qm16   = allocH((size_t)1024 * DD);
    _Float16* a216   = allocH((size_t)1024 * HH);
    _Float16* gl16   = allocH((size_t)1024 * DD);
    _Float16* h216   = allocH((size_t)1024 * DD);
    _Float16* f116   = allocH((size_t)1024 * FFd);

    auto launch = [&](int bm, int nz, const GP& g) {
        dim3 grid((g.N + 127) / 128, (g.M + bm - 1) / bm, nz);
        if (bm == 128) gemm16<128><<<grid, 256, 0, stream>>>(g);
        else           gemm16<64><<<grid, 256, 0, stream>>>(g);
    };

    // ---- init ----
    hipMemcpyAsync(mw0, mem_w0_in, sizeof(float) * DD * HH, hipMemcpyDeviceToDevice, stream);
    hipMemcpyAsync(mw1, mem_w1_in, sizeof(float) * HH * DD, hipMemcpyDeviceToDevice, stream);
    hipMemcpyAsync(mb0, mem_b0_in, sizeof(float) * HH, hipMemcpyDeviceToDevice, stream);
    hipMemcpyAsync(mb1, mem_b1_in, sizeof(float) * DD, hipMemcpyDeviceToDevice, stream);
    zero_k<<<4096, 256, 0, stream>>>(mom, (long)DD * HH * 2 + HH + DD);
    cvt_k<<<(2 * TT * DD) / 1024, 256, 0, stream>>>(x, x16, (long)2 * TT * DD);
    auto T64 = [&](const float* in, _Float16* o, int R, int C) {
        cvtT_k<<<dim3(C / 64, R / 64), 256, 0, stream>>>(in, o, R, C);
    };
    T64(wq_ctx, wqcT, DD, DD);
    T64(wq, wqkT, DD, DD); T64(wk, wqkT + (size_t)1024 * DD, DD, DD);
    T64(wv, wvT, DD, DD); T64(w_attn_out, waoT, DD, DD); T64(w_gate, wgT, DD, DD);
    T64(mem_wk, wmixT, DD, DD); T64(mem_wv, wmixT + (size_t)1024 * DD, DD, DD);
    T64(wq_ctx, wmixT + (size_t)2048 * DD, DD, DD);
    T64(ffn_w1, f1T, DD, FFd); T64(ffn_w2, f2T, FFd, DD);
    T64(mem_w0_in, w0T, DD, HH); T64(mem_w1_in, w1T, HH, DD);
    cvt_k<<<(HH * DD) / 1024, 256, 0, stream>>>(mem_w1_in, w1p, (long)HH * DD);

    for (int c = 0; c < NCH; ++c) {
        GP g;
        // 1. xn_pre = seg @ wq_ctx  (z=2)
        g = GP{}; g.A = x16 + (long)c * CC * DD; g.bsA = (long)TT * DD; g.Bt = wqcT;
        g.Cf = F32A; g.ldc = DD; g.bsC = (long)CC * DD;
        g.s1 = 1.f; g.M = CC; g.N = DD; g.K = DD;
        launch(64, 2, g);
        l2n16s_k<<<1024, 256, 0, stream>>>(F32A, DD, xn16, 1.f);
        // 2. h = mem_mlp(mem, xn)
        g = GP{}; g.A = xn16; g.Bt = w0T; g.bias = mb0; g.Ch = h116; g.ldh = HH;
        g.s1 = 1.f; g.M = 1024; g.N = HH; g.K = DD; g.act = 1;
        launch(64, 1, g);
        g = GP{}; g.A = h116; g.Bt = w1T; g.bias = mb1; g.Cf = F32B; g.ldc = DD;
        g.s1 = 1.f; g.M = 1024; g.N = DD; g.K = HH;
        launch(64, 1, g);
        lnaug_k<<<2 * SB, 256, 0, stream>>>(x, pers, F32B, n1_g, n1_b, laug16, c);
        // 3. q|k fused
        g = GP{}; g.A = laug16; g.Bt = wqkT; g.Cf = F32QK; g.ldc = 2048;
        g.s1 = 1.f; g.M = 2 * SB; g.N = 2048; g.K = DD;
        launch(64, 1, g);
        l2qk_k<<<3104, 256, 0, stream>>>(F32QK, q16, k16);
        // 4. v (transposed out)
        g = GP{}; g.A = laug16; g.bsA = (long)SB * DD; g.Bt = wvT;
        g.Ct = vT16; g.ldt = KA; g.bsT = (long)DD * KA;
        g.s1 = 1.f; g.M = SB; g.N = DD; g.K = DD;
        launch(64, 2, g);
        // 5. scores + softmax + PV
        g = GP{}; g.A = q16; g.bsA = (long)512 * DD; g.Bt = k16; g.bsB = (long)SB * DD;
        g.Cf = F32C; g.ldc = SB; g.bsC = (long)512 * SB;
        g.s1 = 1.f; g.M = 512; g.N = SB; g.K = DD;
        launch(64, 2, g);
        softmax16_k<<<1024, 256, 0, stream>>>(F32C, pr16);
        g = GP{}; g.A = pr16; g.bsA = (long)512 * KA; g.Bt = vT16; g.bsB = (long)DD * KA;
        g.Ch = ao16; g.ldh = DD; g.bsH = (long)512 * DD;
        g.s1 = 1.f; g.M = 512; g.N = DD; g.K = KA;
        launch(64, 2, g);
        // 6. y_t = seg + attn @ wao
        g = GP{}; g.A = ao16; g.bsA = (long)512 * DD; g.Bt = waoT;
        g.resid = x + (long)c * CC * DD; g.ldr = DD; g.bsR = (long)TT * DD;
        g.Cf = YTF; g.ldc = DD; g.bsC = (long)512 * DD;
        g.Ch = yt16; g.ldh = DD; g.bsH = (long)512 * DD;
        g.s1 = 1.f; g.s2 = 1.f; g.M = 512; g.N = DD; g.K = DD;
        launch(64, 2, g);
        // 7. kk | vv | qm_pre fused (act 4) with kkT via LDS transpose
        g = GP{}; g.A = yt16; g.Bt = wmixT; g.Ch = kk16; g.Ct = kkT16; g.ldt = 1024;
        g.Cf = F32B; g.Cf2 = F32A;
        g.s1 = 1.f; g.M = 1024; g.N = 3072; g.K = DD; g.act = 4;
        launch(64, 1, g);
        // 8. a0 = kk@w0+b0 (raw) ; hs/hsT = silu
        g = GP{}; g.A = kk16; g.Bt = w0T; g.bias = mb0; g.Cf = F32C; g.ldc = HH;
        g.Ch = hs16; g.ldh = HH; g.Ct = hsT16; g.ldt = 1024;
        g.s1 = 1.f; g.M = 1024; g.N = HH; g.K = DD; g.act = 1;
        launch(64, 1, g);
        // 9. r = (hs@w1 + b1 - vv)/1024
        g = GP{}; g.A = hs16; g.Bt = w1T; g.bias = mb1;
        g.resid = F32B; g.ldr = DD;
        g.Ch = r16; g.ldh = DD; g.Ct = rT16; g.ldt = 1024;
        g.s1 = 1.f / 1024.f; g.s2 = -1.f / 1024.f; g.M = 1024; g.N = DD; g.K = HH;
        launch(64, 1, g);
        // 10. da0T = (r @ w1_old^T) * dsilu(a0)   (before w1 update!)
        g = GP{}; g.A = r16; g.Bt = w1p; g.aux = F32C; g.ldx = HH;
        g.Ct = da0T; g.ldt = 1024;
        g.s1 = 1.f; g.M = 1024; g.N = HH; g.K = DD; g.act = 2;
        launch(64, 1, g);
        rowsum2_k<<<3072, 256, 0, stream>>>(rT16, da0T, db1, db0);
        // 11. dW1 + momentum + update (act 3): M=H, N=D
        g = GP{}; g.A = hsT16; g.Bt = rT16; g.Cf = mw1; g.ldc = DD; g.Mom = mom_w1;
        g.Ch = w1p; g.ldh = DD; g.Ct = w1T; g.ldt = HH;
        g.M = HH; g.N = DD; g.K = 1024; g.act = 3;
        launch(64, 1, g);
        // 12. dW0 + momentum + update: M=D, N=H
        g = GP{}; g.A = kkT16; g.Bt = da0T; g.Cf = mw0; g.ldc = HH; g.Mom = mom_w0;
        g.Ct = w0T; g.ldt = DD;
        g.M = DD; g.N = HH; g.K = 1024; g.act = 3;
        launch(64, 1, g);
        biasup_k<<<12, 256, 0, stream>>>(mb0, mom_b0, db0, mb1, mom_b1, db1);
        // 13. mem_out = mem_mlp(new mem, l2norm(qm_pre))
        l2n16s_k<<<1024, 256, 0, stream>>>(F32A, DD, qm16, 1.f);
        g = GP{}; g.A = qm16; g.Bt = w0T; g.bias = mb0; g.Ch = a216; g.ldh = HH;
        g.s1 = 1.f; g.M = 1024; g.N = HH; g.K = DD; g.act = 1;
        launch(64, 1, g);
        g = GP{}; g.A = a216; g.Bt = w1T; g.bias = mb1; g.Cf = F32B; g.ldc = DD;
        g.s1 = 1.f; g.M = 1024; g.N = DD; g.K = HH;
        launch(64, 1, g);
        // 14. gate
        ln16_k<<<1024, 256, 0, stream>>>(YTF, gate_g, gate_b, gl16);
        g = GP{}; g.A = gl16; g.Bt = wgT; g.Cf = F32C; g.ldc = DD;
        g.s1 = 1.f; g.M = 1024; g.N = DD; g.K = DD;
        launch(64, 1, g);
        gateln2_k<<<1024, 256, 0, stream>>>(YTF, F32C, F32B, n2_g, n2_b, OF, h216);
        // 15. FFN
        g = GP{}; g.A = h216; g.Bt = f1T; g.bias = ffn_b1; g.Ch = f116; g.ldh = FFd;
        g.s1 = 1.f; g.M = 1024; g.N = FFd; g.K = DD; g.act = 1;
        launch(128, 1, g);
        g = GP{}; g.A = f116; g.bsA = (long)512 * FFd; g.Bt = f2T; g.bias = ffn_b2;
        g.resid = OF; g.ldr = DD; g.bsR = (long)512 * DD;
        g.Cf = out + (long)c * CC * DD; g.ldc = DD; g.bsC = (long)TT * DD;
        g.s1 = 1.f; g.s2 = 1.f; g.M = 512; g.N = DD; g.K = FFd;
        launch(64, 2, g);
    }
}